// Round 5
// baseline (1616.810 us; speedup 1.0000x reference)
//
#include <hip/hip_runtime.h>

// ResGCN: 3x GCNConv(+BN+ReLU, residual), N=100k, E=1.6M.
// R5: kill k_fill's 107MB write-allocate. Blocked radix bucket-sort of edges
// (bucket = dst>>6, block-exclusive output regions -> full-line writes),
// then bucketed LDS-accumulator aggregation straight off sorted pairs
// (no csrc/rowstart needed). b0/b1 skipped (cancelled by BN mean-sub).

#define NN 100000
#define NE 1600000
#define NBUCK 1563        // ceil(NN/64), bucket = dst >> 6
#define NBLK 256          // sort blocks
#define CHUNK 6250        // NE / NBLK exact

// ---- pass A: per-block bucket histogram (transposed: H[bucket*NBLK + blk]) ----
__launch_bounds__(256)
__global__ void kA_hist(const int* __restrict__ dst, int* __restrict__ H) {
    __shared__ int h[NBUCK];
    int t = threadIdx.x, blk = blockIdx.x;
    for (int b = t; b < NBUCK; b += 256) h[b] = 0;
    __syncthreads();
    int e0 = blk * CHUNK;
    for (int e = e0 + t; e < e0 + CHUNK; e += 256) atomicAdd(&h[dst[e] >> 6], 1);
    __syncthreads();
    for (int b = t; b < NBUCK; b += 256) H[b * NBLK + blk] = h[b];
}

// ---- pass B1: bucket totals ----
__launch_bounds__(256)
__global__ void kB1(const int* __restrict__ H, int* __restrict__ bsum) {
    __shared__ int sh[256];
    int b = blockIdx.x, t = threadIdx.x;
    sh[t] = H[b * NBLK + t];
    __syncthreads();
    for (int s = 128; s; s >>= 1) {
        if (t < s) sh[t] += sh[t + s];
        __syncthreads();
    }
    if (t == 0) bsum[b] = sh[0];
}
// ---- pass B2: exclusive scan of bucket totals -> bbase[0..NBUCK] ----
__global__ void kB2(const int* __restrict__ bsum, int* __restrict__ bbase) {
    __shared__ int sh[NBUCK];
    int t = threadIdx.x;
    for (int b = t; b < NBUCK; b += 256) sh[b] = bsum[b];
    __syncthreads();
    if (t == 0) {
        int acc = 0;
        for (int b = 0; b < NBUCK; ++b) { int v = sh[b]; sh[b] = acc; acc += v; }
        bbase[NBUCK] = acc;  // == NE
    }
    __syncthreads();
    for (int b = t; b < NBUCK; b += 256) bbase[b] = sh[b];
}
// ---- pass B3: per-(bucket,blk) offsets, written in place over H ----
__launch_bounds__(256)
__global__ void kB3(int* __restrict__ H, const int* __restrict__ bbase) {
    __shared__ int sh[256];
    int b = blockIdx.x, t = threadIdx.x;
    sh[t] = H[b * NBLK + t];
    __syncthreads();
    if (t == 0) {
        int acc = bbase[b];
        for (int i = 0; i < 256; ++i) { int v = sh[i]; sh[i] = acc; acc += v; }
    }
    __syncthreads();
    H[b * NBLK + t] = sh[t];
}

// ---- pass C: scatter (dst,src) pairs into bucket-sorted order ----
__launch_bounds__(256)
__global__ void kC_scatter(const int* __restrict__ src, const int* __restrict__ dst,
                           const int* __restrict__ O, int2* __restrict__ sorted) {
    __shared__ int cur[NBUCK];
    int t = threadIdx.x, blk = blockIdx.x;
    for (int b = t; b < NBUCK; b += 256) cur[b] = O[b * NBLK + blk];
    __syncthreads();
    int e0 = blk * CHUNK;
    for (int e = e0 + t; e < e0 + CHUNK; e += 256) {
        int d = dst[e], s = src[e];
        int p = atomicAdd(&cur[d >> 6], 1);
        sorted[p] = make_int2(d, s);
    }
}

// ---- pass D: per-node degree -> dinv ----
__launch_bounds__(256)
__global__ void kD_deg(const int2* __restrict__ sorted, const int* __restrict__ bbase,
                       float* __restrict__ dinv) {
    __shared__ int cnt[64];
    int b = blockIdx.x, t = threadIdx.x;
    if (t < 64) cnt[t] = 0;
    __syncthreads();
    int beg = bbase[b], end = bbase[b + 1];
    for (int i = beg + t; i < end; i += 256) atomicAdd(&cnt[sorted[i].x & 63], 1);
    __syncthreads();
    int node = b * 64 + t;
    if (t < 64 && node < NN) dinv[node] = rsqrtf((float)(cnt[t] + 1));
}

// ---- fused GEMM (N x 64) @ (64 x 64), epilogue premult by dinv ----
// MODE 0: Yp = dinv * (X @ W)
// MODE 1: a = relu(bn(X)); side = a; Yp = dinv * (a @ W)
template <int MODE>
__launch_bounds__(256)
__global__ void k_gemm64(const float* __restrict__ X, const float* __restrict__ W,
                         const float* __restrict__ scsh, const float* __restrict__ dinv,
                         float* __restrict__ Yp, float* __restrict__ side) {
    __shared__ float Ws[64 * 64];
    __shared__ float xs[4][64];
    int t = threadIdx.x;
#pragma unroll
    for (int i = 0; i < 16; ++i) Ws[t + 256 * i] = W[t + 256 * i];
    int c = t & 63, rr = t >> 6;
    float scale = 1.f, shift = 0.f;
    if (MODE == 1) { scale = scsh[c]; shift = scsh[64 + c]; }
    int base = blockIdx.x * 256;
    for (int rb = 0; rb < 64; ++rb) {
        int row = base + rb * 4 + rr;
        float v = 0.f;
        if (row < NN) {
            v = X[row * 64 + c];
            if (MODE == 1) {
                v = fmaxf(fmaf(v, scale, shift), 0.f);
                side[row * 64 + c] = v;
            }
        }
        xs[rr][c] = v;
        __syncthreads();
        if (row < NN) {
            float acc = 0.f;
#pragma unroll
            for (int k = 0; k < 64; ++k) acc = fmaf(xs[rr][k], Ws[k * 64 + c], acc);
            Yp[row * 64 + c] = dinv[row] * acc;
        }
        __syncthreads();
    }
}

// ---- bucketed aggregation: agg[d] = dinv[d]*(Yp[d] + sum Yp[src]) ----
// one block per bucket; 64x64 LDS accumulator; 2 edges in flight per wave.
__launch_bounds__(256)
__global__ void kE_agg(const float* __restrict__ Yp, const int2* __restrict__ sorted,
                       const int* __restrict__ bbase, const float* __restrict__ dinv,
                       float* __restrict__ agg) {
    __shared__ float acc[64][64];  // 16 KB
    int b = blockIdx.x, t = threadIdx.x;
    int c = t & 63, r4 = t >> 6;
    int node0 = b * 64;
    int nn = min(64, NN - node0);
    for (int n = r4; n < nn; n += 4) acc[n][c] = Yp[(node0 + n) * 64 + c];  // self loop
    __syncthreads();
    int beg = bbase[b], end = bbase[b + 1];
    for (int i = beg + (r4 << 1); i < end; i += 8) {
        int2 pa = sorted[i];
        bool hb = (i + 1 < end);
        int2 pb = hb ? sorted[i + 1] : pa;
        float va = Yp[pa.y * 64 + c];
        float vb = hb ? Yp[pb.y * 64 + c] : 0.f;
        atomicAdd(&acc[pa.x & 63][c], va);
        if (hb) atomicAdd(&acc[pb.x & 63][c], vb);
    }
    __syncthreads();
    for (int n = r4; n < nn; n += 4)
        agg[(node0 + n) * 64 + c] = dinv[node0 + n] * acc[n][c];
}

// ---- BatchNorm stats ----
__launch_bounds__(256)
__global__ void k_bn_stats(const float* __restrict__ X, float* __restrict__ stats) {
    __shared__ float sh[512];
    int t = threadIdx.x;
    int c = t & 63, rr = t >> 6;
    float sum = 0.f, sq = 0.f;
    for (int r = blockIdx.x * 4 + rr; r < NN; r += gridDim.x * 4) {
        float v = X[r * 64 + c];
        sum += v;
        sq = fmaf(v, v, sq);
    }
    sh[t] = sum;
    sh[256 + t] = sq;
    __syncthreads();
    if (t < 64) {
        float s = sh[t] + sh[t + 64] + sh[t + 128] + sh[t + 192];
        float q = sh[256 + t] + sh[320 + t] + sh[384 + t] + sh[448 + t];
        atomicAdd(&stats[t], s);
        atomicAdd(&stats[64 + t], q);
    }
}
__global__ void k_bn_final(const float* __restrict__ stats, const float* __restrict__ g,
                           const float* __restrict__ be, float* __restrict__ scsh) {
    int c = threadIdx.x;
    if (c < 64) {
        float mean = stats[c] * (1.0f / NN);
        float var = stats[64 + c] * (1.0f / NN) - mean * mean;
        float sc = g[c] * rsqrtf(var + 1e-5f);
        scsh[c] = sc;
        scsh[64 + c] = be[c] - mean * sc;
    }
}

// ---- final layer GEMM: Tp = dinv * ((relu(bn(X)) + R) @ W2) ----
__launch_bounds__(256)
__global__ void k_gemm_out2(const float* __restrict__ X, const float* __restrict__ scsh,
                            const float* __restrict__ R, const float* __restrict__ W2,
                            const float* __restrict__ dinv, float* __restrict__ Tp) {
    int t = threadIdx.x;
    int lane = t & 63, wv = t >> 6;
    int row = blockIdx.x * 4 + wv;
    if (row >= NN) return;
    float w0 = W2[lane * 2], w1 = W2[lane * 2 + 1];
    float scale = scsh[lane], shift = scsh[64 + lane];
    float v = X[row * 64 + lane];
    v = fmaxf(fmaf(v, scale, shift), 0.f) + R[row * 64 + lane];
    float p0 = v * w0, p1 = v * w1;
#pragma unroll
    for (int s = 32; s; s >>= 1) {
        p0 += __shfl_xor(p0, s);
        p1 += __shfl_xor(p1, s);
    }
    if (lane == 0) {
        float d = dinv[row];
        Tp[row * 2] = d * p0;
        Tp[row * 2 + 1] = d * p1;
    }
}

// ---- final bucketed aggregation, 2 channels ----
__launch_bounds__(256)
__global__ void kF_out(const float* __restrict__ Tp, const int2* __restrict__ sorted,
                       const int* __restrict__ bbase, const float* __restrict__ dinv,
                       const float* __restrict__ b2, float* __restrict__ out) {
    __shared__ float acc[128];  // 64 nodes x 2 ch
    int b = blockIdx.x, t = threadIdx.x;
    int node0 = b * 64, nn = min(64, NN - node0);
    if (t < 2 * nn) acc[t] = Tp[node0 * 2 + t];  // self loop
    __syncthreads();
    int beg = bbase[b], end = bbase[b + 1];
    for (int i = beg + t; i < end; i += 256) {
        int2 p = sorted[i];
        float2 v = ((const float2*)Tp)[p.y];
        int d = (p.x & 63) * 2;
        atomicAdd(&acc[d], v.x);
        atomicAdd(&acc[d + 1], v.y);
    }
    __syncthreads();
    if (t < 2 * nn) {
        int node = node0 + (t >> 1);
        out[node0 * 2 + t] = dinv[node] * acc[t] + b2[t & 1];
    }
}

extern "C" void kernel_launch(void* const* d_in, const int* in_sizes, int n_in,
                              void* d_out, int out_size, void* d_ws, size_t ws_size,
                              hipStream_t stream) {
    const float* x   = (const float*)d_in[0];
    const int*   ei  = (const int*)d_in[1];
    const int*   src = ei;
    const int*   dst = ei + NE;
    const float* W0  = (const float*)d_in[2];
    const float* g0  = (const float*)d_in[4];
    const float* be0 = (const float*)d_in[5];
    const float* W1  = (const float*)d_in[6];
    const float* g1  = (const float*)d_in[8];
    const float* be1 = (const float*)d_in[9];
    const float* W2  = (const float*)d_in[10];
    const float* b2  = (const float*)d_in[11];
    float* out = (float*)d_out;

    int*   H      = (int*)d_ws;               // NBUCK*NBLK = 400128 (offsets in place)
    int*   bsum   = H + NBUCK * NBLK;         // pad 2048
    int*   bbase  = bsum + 2048;              // pad 2048 (NBUCK+1 used)
    int2*  sorted = (int2*)(bbase + 2048);    // NE pairs (8B-aligned: offset even)
    float* dinv   = (float*)(sorted + NE);    // N
    float* A      = dinv + NN;                // N*64  (Yp)
    float* B      = A + NN * 64;              // N*64  (agg)
    float* C      = B + NN * 64;              // N*64  (hres)
    float* Tp     = C + NN * 64;              // N*2
    float* stats0 = Tp + NN * 2;              // 128
    float* stats1 = stats0 + 128;             // 128
    float* scsh0  = stats1 + 128;             // 128
    float* scsh1  = scsh0 + 128;              // 128

    hipMemsetAsync(stats0, 0, 256 * sizeof(float), stream);

    // bucket sort of edges by dst>>6
    kA_hist<<<NBLK, 256, 0, stream>>>(dst, H);
    kB1<<<NBUCK, 256, 0, stream>>>(H, bsum);
    kB2<<<1, 256, 0, stream>>>(bsum, bbase);
    kB3<<<NBUCK, 256, 0, stream>>>(H, bbase);
    kC_scatter<<<NBLK, 256, 0, stream>>>(src, dst, H, sorted);
    kD_deg<<<NBUCK, 256, 0, stream>>>(sorted, bbase, dinv);

    int gemmGrid = (NN + 255) / 256;

    // layer 0
    k_gemm64<0><<<gemmGrid, 256, 0, stream>>>(x, W0, nullptr, dinv, A, nullptr);
    kE_agg<<<NBUCK, 256, 0, stream>>>(A, sorted, bbase, dinv, B);
    k_bn_stats<<<256, 256, 0, stream>>>(B, stats0);
    k_bn_final<<<1, 64, 0, stream>>>(stats0, g0, be0, scsh0);

    // layer 1
    k_gemm64<1><<<gemmGrid, 256, 0, stream>>>(B, W1, scsh0, dinv, A, C);
    kE_agg<<<NBUCK, 256, 0, stream>>>(A, sorted, bbase, dinv, B);
    k_bn_stats<<<256, 256, 0, stream>>>(B, stats1);
    k_bn_final<<<1, 64, 0, stream>>>(stats1, g1, be1, scsh1);

    // layer 2
    k_gemm_out2<<<(NN + 3) / 4, 256, 0, stream>>>(B, scsh1, C, W2, dinv, Tp);
    kF_out<<<NBUCK, 256, 0, stream>>>(Tp, sorted, bbase, dinv, b2, out);
}

// Round 6
// 528.055 us; speedup vs baseline: 3.0618x; 3.0618x over previous
//
#include <hip/hip_runtime.h>

// ResGCN: 3x GCNConv(+BN+ReLU, residual), N=100k, E=1.6M.
// R6: R4 structure (one-wave-per-node CSR gather aggregation = max TLP) with a
// cheap CSR build: bucket-sort by dst>>6 (packed u32, block-exclusive regions)
// + per-bucket LDS finalize writing csrc densely (no 107MB write-allocate).
// R5 lesson: blocked LDS-accum agg was latency-bound (4.5% BW, 12k edges in
// flight vs 400k here). b0/b1 skipped (cancelled by BN mean-sub).

#define NN 100000
#define NE 1600000
#define NBUCK 1563        // ceil(NN/64); bucket = dst >> 6
#define NBLK 256          // sort blocks
#define CHUNK 6250        // NE / NBLK exact
#define MAXB 2048         // LDS finalize capacity (avg bucket = 1024, Poisson)

// ---- pass A: per-block bucket histogram (transposed: H[bucket*NBLK + blk]) ----
__launch_bounds__(256)
__global__ void kA_hist(const int* __restrict__ dst, int* __restrict__ H) {
    __shared__ int h[NBUCK];
    int t = threadIdx.x, blk = blockIdx.x;
    for (int b = t; b < NBUCK; b += 256) h[b] = 0;
    __syncthreads();
    int e0 = blk * CHUNK;
    for (int e = e0 + t; e < e0 + CHUNK; e += 256) atomicAdd(&h[dst[e] >> 6], 1);
    __syncthreads();
    for (int b = t; b < NBUCK; b += 256) H[b * NBLK + blk] = h[b];
}
// ---- pass B1: bucket totals ----
__launch_bounds__(256)
__global__ void kB1(const int* __restrict__ H, int* __restrict__ bsum) {
    __shared__ int sh[256];
    int b = blockIdx.x, t = threadIdx.x;
    sh[t] = H[b * NBLK + t];
    __syncthreads();
    for (int s = 128; s; s >>= 1) {
        if (t < s) sh[t] += sh[t + s];
        __syncthreads();
    }
    if (t == 0) bsum[b] = sh[0];
}
// ---- pass B2: exclusive scan of bucket totals -> bbase[0..NBUCK] ----
__global__ void kB2(const int* __restrict__ bsum, int* __restrict__ bbase) {
    __shared__ int sh[NBUCK];
    int t = threadIdx.x;
    for (int b = t; b < NBUCK; b += 256) sh[b] = bsum[b];
    __syncthreads();
    if (t == 0) {
        int acc = 0;
        for (int b = 0; b < NBUCK; ++b) { int v = sh[b]; sh[b] = acc; acc += v; }
        bbase[NBUCK] = acc;  // == NE
    }
    __syncthreads();
    for (int b = t; b < NBUCK; b += 256) bbase[b] = sh[b];
}
// ---- pass B3: per-(bucket,blk) offsets, in place over H ----
__launch_bounds__(256)
__global__ void kB3(int* __restrict__ H, const int* __restrict__ bbase) {
    __shared__ int sh[256];
    int b = blockIdx.x, t = threadIdx.x;
    sh[t] = H[b * NBLK + t];
    __syncthreads();
    if (t == 0) {
        int acc = bbase[b];
        for (int i = 0; i < 256; ++i) { int v = sh[i]; sh[i] = acc; acc += v; }
    }
    __syncthreads();
    H[b * NBLK + t] = sh[t];
}
// ---- pass C: scatter packed (node6|src24) into bucket order ----
__launch_bounds__(256)
__global__ void kC_scatter(const int* __restrict__ src, const int* __restrict__ dst,
                           const int* __restrict__ O, unsigned int* __restrict__ sp) {
    __shared__ int cur[NBUCK];
    int t = threadIdx.x, blk = blockIdx.x;
    for (int b = t; b < NBUCK; b += 256) cur[b] = O[b * NBLK + blk];
    __syncthreads();
    int e0 = blk * CHUNK;
    for (int e = e0 + t; e < e0 + CHUNK; e += 256) {
        int d = dst[e], s = src[e];
        int p = atomicAdd(&cur[d >> 6], 1);
        sp[p] = ((unsigned int)(d & 63) << 24) | (unsigned int)s;
    }
}
// ---- pass D: per-bucket CSR finalize: csrc dense, rowstart/cnt/dinv ----
__launch_bounds__(256)
__global__ void kD2_fin(const unsigned int* __restrict__ sp, const int* __restrict__ bbase,
                        int* __restrict__ csrc, int* __restrict__ rowstart,
                        int* __restrict__ cntg, float* __restrict__ dinv) {
    __shared__ int cnt[64], ofs[64], cur[64];
    __shared__ int tmp[MAXB];
    int b = blockIdx.x, t = threadIdx.x;
    int beg = bbase[b], end = bbase[b + 1], n = end - beg;
    if (t < 64) cnt[t] = 0;
    __syncthreads();
    for (int i = beg + t; i < end; i += 256) atomicAdd(&cnt[sp[i] >> 24], 1);
    __syncthreads();
    if (t == 0) {
        int acc = 0;
        for (int k = 0; k < 64; ++k) { int v = cnt[k]; ofs[k] = acc; cur[k] = acc; acc += v; }
    }
    __syncthreads();
    int node = b * 64 + t;
    if (t < 64 && node < NN) {
        rowstart[node] = beg + ofs[t];
        cntg[node] = cnt[t];
        dinv[node] = rsqrtf((float)(cnt[t] + 1));
    }
    if (n <= MAXB) {
        for (int i = beg + t; i < end; i += 256) {
            unsigned int v = sp[i];
            int p = atomicAdd(&cur[v >> 24], 1);
            tmp[p] = (int)(v & 0xFFFFFFu);
        }
        __syncthreads();
        for (int i = t; i < n; i += 256) csrc[beg + i] = tmp[i];  // dense, full lines
    } else {  // safety fallback (statistically unreachable for this graph)
        for (int i = beg + t; i < end; i += 256) {
            unsigned int v = sp[i];
            int p = atomicAdd(&cur[v >> 24], 1);
            csrc[beg + p] = (int)(v & 0xFFFFFFu);
        }
    }
}

// ---- fused GEMM (N x 64) @ (64 x 64), epilogue premult by dinv ----
// MODE 0: Yp = dinv * (X @ W)
// MODE 1: a = relu(bn(X)); side = a; Yp = dinv * (a @ W)
template <int MODE>
__launch_bounds__(256)
__global__ void k_gemm64(const float* __restrict__ X, const float* __restrict__ W,
                         const float* __restrict__ scsh, const float* __restrict__ dinv,
                         float* __restrict__ Yp, float* __restrict__ side) {
    __shared__ float Ws[64 * 64];
    __shared__ float xs[4][64];
    int t = threadIdx.x;
#pragma unroll
    for (int i = 0; i < 16; ++i) Ws[t + 256 * i] = W[t + 256 * i];
    int c = t & 63, rr = t >> 6;
    float scale = 1.f, shift = 0.f;
    if (MODE == 1) { scale = scsh[c]; shift = scsh[64 + c]; }
    int base = blockIdx.x * 256;
    for (int rb = 0; rb < 64; ++rb) {
        int row = base + rb * 4 + rr;
        float v = 0.f;
        if (row < NN) {
            v = X[row * 64 + c];
            if (MODE == 1) {
                v = fmaxf(fmaf(v, scale, shift), 0.f);
                side[row * 64 + c] = v;
            }
        }
        xs[rr][c] = v;
        __syncthreads();
        if (row < NN) {
            float acc = 0.f;
#pragma unroll
            for (int k = 0; k < 64; ++k) acc = fmaf(xs[rr][k], Ws[k * 64 + c], acc);
            Yp[row * 64 + c] = dinv[row] * acc;
        }
        __syncthreads();
    }
}

// ---- CSR aggregation: agg[d] = dinv[d]*(Yp[d] + sum Yp[src]); 1 wave/node ----
__launch_bounds__(256)
__global__ void k_agg_csr(const float* __restrict__ Yp, const int* __restrict__ rowstart,
                          const int* __restrict__ cnt, const int* __restrict__ csrc,
                          const float* __restrict__ dinv, float* __restrict__ agg) {
    int wid = (blockIdx.x * blockDim.x + threadIdx.x) >> 6;  // node
    int lane = threadIdx.x & 63;
    if (wid >= NN) return;
    int grp = lane >> 4;  // 0..3: edge slot
    int l16 = lane & 15;  // float4 channel quad
    int beg = rowstart[wid], n = cnt[wid];
    float4 acc = {0.f, 0.f, 0.f, 0.f};
    if (grp == 0) acc = ((const float4*)(Yp + (long)wid * 64))[l16];  // self loop
    int j = grp;
    for (; j + 4 < n; j += 8) {  // 2 edges in flight per lane-group
        int s0 = csrc[beg + j];
        int s1 = csrc[beg + j + 4];
        float4 v0 = ((const float4*)(Yp + (long)s0 * 64))[l16];
        float4 v1 = ((const float4*)(Yp + (long)s1 * 64))[l16];
        acc.x += v0.x + v1.x; acc.y += v0.y + v1.y;
        acc.z += v0.z + v1.z; acc.w += v0.w + v1.w;
    }
    if (j < n) {
        int s = csrc[beg + j];
        float4 v = ((const float4*)(Yp + (long)s * 64))[l16];
        acc.x += v.x; acc.y += v.y; acc.z += v.z; acc.w += v.w;
    }
#pragma unroll
    for (int m = 16; m <= 32; m <<= 1) {
        acc.x += __shfl_xor(acc.x, m);
        acc.y += __shfl_xor(acc.y, m);
        acc.z += __shfl_xor(acc.z, m);
        acc.w += __shfl_xor(acc.w, m);
    }
    if (grp == 0) {
        float d = dinv[wid];
        float4 r = {acc.x * d, acc.y * d, acc.z * d, acc.w * d};
        ((float4*)(agg + (long)wid * 64))[l16] = r;
    }
}

// ---- BatchNorm stats ----
__launch_bounds__(256)
__global__ void k_bn_stats(const float* __restrict__ X, float* __restrict__ stats) {
    __shared__ float sh[512];
    int t = threadIdx.x;
    int c = t & 63, rr = t >> 6;
    float sum = 0.f, sq = 0.f;
    for (int r = blockIdx.x * 4 + rr; r < NN; r += gridDim.x * 4) {
        float v = X[r * 64 + c];
        sum += v;
        sq = fmaf(v, v, sq);
    }
    sh[t] = sum;
    sh[256 + t] = sq;
    __syncthreads();
    if (t < 64) {
        float s = sh[t] + sh[t + 64] + sh[t + 128] + sh[t + 192];
        float q = sh[256 + t] + sh[320 + t] + sh[384 + t] + sh[448 + t];
        atomicAdd(&stats[t], s);
        atomicAdd(&stats[64 + t], q);
    }
}
__global__ void k_bn_final(const float* __restrict__ stats, const float* __restrict__ g,
                           const float* __restrict__ be, float* __restrict__ scsh) {
    int c = threadIdx.x;
    if (c < 64) {
        float mean = stats[c] * (1.0f / NN);
        float var = stats[64 + c] * (1.0f / NN) - mean * mean;
        float sc = g[c] * rsqrtf(var + 1e-5f);
        scsh[c] = sc;
        scsh[64 + c] = be[c] - mean * sc;
    }
}

// ---- final layer GEMM: Tp = dinv * ((relu(bn(X)) + R) @ W2) ----
__launch_bounds__(256)
__global__ void k_gemm_out2(const float* __restrict__ X, const float* __restrict__ scsh,
                            const float* __restrict__ R, const float* __restrict__ W2,
                            const float* __restrict__ dinv, float* __restrict__ Tp) {
    int t = threadIdx.x;
    int lane = t & 63, wv = t >> 6;
    int row = blockIdx.x * 4 + wv;
    if (row >= NN) return;
    float w0 = W2[lane * 2], w1 = W2[lane * 2 + 1];
    float scale = scsh[lane], shift = scsh[64 + lane];
    float v = X[row * 64 + lane];
    v = fmaxf(fmaf(v, scale, shift), 0.f) + R[row * 64 + lane];
    float p0 = v * w0, p1 = v * w1;
#pragma unroll
    for (int s = 32; s; s >>= 1) {
        p0 += __shfl_xor(p0, s);
        p1 += __shfl_xor(p1, s);
    }
    if (lane == 0) {
        float d = dinv[row];
        Tp[row * 2] = d * p0;
        Tp[row * 2 + 1] = d * p1;
    }
}

// ---- final CSR aggregation, 2 channels, 8 lanes/node ----
__launch_bounds__(256)
__global__ void k_out_csr(const float* __restrict__ Tp, const int* __restrict__ rowstart,
                          const int* __restrict__ cnt, const int* __restrict__ csrc,
                          const float* __restrict__ dinv, const float* __restrict__ b2,
                          float* __restrict__ out) {
    int id = blockIdx.x * blockDim.x + threadIdx.x;
    int node = id >> 3, l = id & 7;
    if (node >= NN) return;
    int beg = rowstart[node], n = cnt[node];
    float a0 = 0.f, a1 = 0.f;
    if (l == 0) { a0 = Tp[node * 2]; a1 = Tp[node * 2 + 1]; }  // self loop
    for (int j = l; j < n; j += 8) {
        int s = csrc[beg + j];
        a0 += Tp[s * 2];
        a1 += Tp[s * 2 + 1];
    }
#pragma unroll
    for (int m = 1; m < 8; m <<= 1) {
        a0 += __shfl_xor(a0, m);
        a1 += __shfl_xor(a1, m);
    }
    if (l == 0) {
        float d = dinv[node];
        out[node * 2] = d * a0 + b2[0];
        out[node * 2 + 1] = d * a1 + b2[1];
    }
}

extern "C" void kernel_launch(void* const* d_in, const int* in_sizes, int n_in,
                              void* d_out, int out_size, void* d_ws, size_t ws_size,
                              hipStream_t stream) {
    const float* x   = (const float*)d_in[0];
    const int*   ei  = (const int*)d_in[1];
    const int*   src = ei;
    const int*   dst = ei + NE;
    const float* W0  = (const float*)d_in[2];
    const float* g0  = (const float*)d_in[4];
    const float* be0 = (const float*)d_in[5];
    const float* W1  = (const float*)d_in[6];
    const float* g1  = (const float*)d_in[8];
    const float* be1 = (const float*)d_in[9];
    const float* W2  = (const float*)d_in[10];
    const float* b2  = (const float*)d_in[11];
    float* out = (float*)d_out;

    int*   H      = (int*)d_ws;                    // NBUCK*NBLK ints (1.6MB)
    int*   bsum   = H + NBUCK * NBLK;              // pad 2048
    int*   bbase  = bsum + 2048;                   // pad 2048 (NBUCK+1 used)
    unsigned int* sp = (unsigned int*)(bbase + 2048);  // NE packed
    int*   csrc   = (int*)(sp + NE);               // NE
    int*   rowstart = csrc + NE;                   // N
    int*   cntg   = rowstart + NN;                 // N
    float* dinv   = (float*)(cntg + NN);           // N
    float* A      = dinv + NN;                     // N*64 (Yp)
    float* B      = A + NN * 64;                   // N*64 (agg)
    float* C      = B + NN * 64;                   // N*64 (hres)
    float* Tp     = C + NN * 64;                   // N*2
    float* stats0 = Tp + NN * 2;                   // 128
    float* stats1 = stats0 + 128;                  // 128
    float* scsh0  = stats1 + 128;                  // 128
    float* scsh1  = scsh0 + 128;                   // 128

    hipMemsetAsync(stats0, 0, 256 * sizeof(float), stream);

    // CSR build: bucket sort by dst>>6, then per-bucket LDS finalize
    kA_hist<<<NBLK, 256, 0, stream>>>(dst, H);
    kB1<<<NBUCK, 256, 0, stream>>>(H, bsum);
    kB2<<<1, 256, 0, stream>>>(bsum, bbase);
    kB3<<<NBUCK, 256, 0, stream>>>(H, bbase);
    kC_scatter<<<NBLK, 256, 0, stream>>>(src, dst, H, sp);
    kD2_fin<<<NBUCK, 256, 0, stream>>>(sp, bbase, csrc, rowstart, cntg, dinv);

    int gemmGrid = (NN + 255) / 256;
    int aggGrid  = (NN * 64) / 256;  // one wave per node, exact

    // layer 0
    k_gemm64<0><<<gemmGrid, 256, 0, stream>>>(x, W0, nullptr, dinv, A, nullptr);
    k_agg_csr<<<aggGrid, 256, 0, stream>>>(A, rowstart, cntg, csrc, dinv, B);
    k_bn_stats<<<256, 256, 0, stream>>>(B, stats0);
    k_bn_final<<<1, 64, 0, stream>>>(stats0, g0, be0, scsh0);

    // layer 1
    k_gemm64<1><<<gemmGrid, 256, 0, stream>>>(B, W1, scsh0, dinv, A, C);
    k_agg_csr<<<aggGrid, 256, 0, stream>>>(A, rowstart, cntg, csrc, dinv, B);
    k_bn_stats<<<256, 256, 0, stream>>>(B, stats1);
    k_bn_final<<<1, 64, 0, stream>>>(stats1, g1, be1, scsh1);

    // layer 2
    k_gemm_out2<<<(NN + 3) / 4, 256, 0, stream>>>(B, scsh1, C, W2, dinv, Tp);
    k_out_csr<<<(NN * 8 + 255) / 256, 256, 0, stream>>>(Tp, rowstart, cntg, csrc, dinv, b2, out);
}

// Round 8
// 489.796 us; speedup vs baseline: 3.3010x; 1.0781x over previous
//
#include <hip/hip_runtime.h>

// ResGCN: 3x GCNConv(+BN+ReLU, residual), N=100k, E=1.6M.
// R7 (resubmit — broker timeout, no data): R6 + gemm64 de-starvation.
// R6 counters: k_gemm64 occupancy 14% (391 blocks only), VALUBusy 14% ->
// latency-bound serial FMA chain. Fix: 64 rows/block (grid 1563) + 4-way
// split accumulators. Rest unchanged. b0/b1 skipped (cancelled by BN mean-sub).

#define NN 100000
#define NE 1600000
#define NBUCK 1563        // ceil(NN/64); bucket = dst >> 6
#define NBLK 256          // sort blocks
#define CHUNK 6250        // NE / NBLK exact
#define MAXB 2048         // LDS finalize capacity (avg bucket = 1024)

// ---- pass A: per-block bucket histogram (transposed: H[bucket*NBLK + blk]) ----
__launch_bounds__(256)
__global__ void kA_hist(const int* __restrict__ dst, int* __restrict__ H) {
    __shared__ int h[NBUCK];
    int t = threadIdx.x, blk = blockIdx.x;
    for (int b = t; b < NBUCK; b += 256) h[b] = 0;
    __syncthreads();
    int e0 = blk * CHUNK;
    for (int e = e0 + t; e < e0 + CHUNK; e += 256) atomicAdd(&h[dst[e] >> 6], 1);
    __syncthreads();
    for (int b = t; b < NBUCK; b += 256) H[b * NBLK + blk] = h[b];
}
// ---- pass B1: bucket totals ----
__launch_bounds__(256)
__global__ void kB1(const int* __restrict__ H, int* __restrict__ bsum) {
    __shared__ int sh[256];
    int b = blockIdx.x, t = threadIdx.x;
    sh[t] = H[b * NBLK + t];
    __syncthreads();
    for (int s = 128; s; s >>= 1) {
        if (t < s) sh[t] += sh[t + s];
        __syncthreads();
    }
    if (t == 0) bsum[b] = sh[0];
}
// ---- pass B2: exclusive scan of bucket totals -> bbase[0..NBUCK] ----
__global__ void kB2(const int* __restrict__ bsum, int* __restrict__ bbase) {
    __shared__ int sh[NBUCK];
    int t = threadIdx.x;
    for (int b = t; b < NBUCK; b += 256) sh[b] = bsum[b];
    __syncthreads();
    if (t == 0) {
        int acc = 0;
        for (int b = 0; b < NBUCK; ++b) { int v = sh[b]; sh[b] = acc; acc += v; }
        bbase[NBUCK] = acc;  // == NE
    }
    __syncthreads();
    for (int b = t; b < NBUCK; b += 256) bbase[b] = sh[b];
}
// ---- pass B3: per-(bucket,blk) offsets, in place over H ----
__launch_bounds__(256)
__global__ void kB3(int* __restrict__ H, const int* __restrict__ bbase) {
    __shared__ int sh[256];
    int b = blockIdx.x, t = threadIdx.x;
    sh[t] = H[b * NBLK + t];
    __syncthreads();
    if (t == 0) {
        int acc = bbase[b];
        for (int i = 0; i < 256; ++i) { int v = sh[i]; sh[i] = acc; acc += v; }
    }
    __syncthreads();
    H[b * NBLK + t] = sh[t];
}
// ---- pass C: scatter packed (node6|src24) into bucket order ----
__launch_bounds__(256)
__global__ void kC_scatter(const int* __restrict__ src, const int* __restrict__ dst,
                           const int* __restrict__ O, unsigned int* __restrict__ sp) {
    __shared__ int cur[NBUCK];
    int t = threadIdx.x, blk = blockIdx.x;
    for (int b = t; b < NBUCK; b += 256) cur[b] = O[b * NBLK + blk];
    __syncthreads();
    int e0 = blk * CHUNK;
    for (int e = e0 + t; e < e0 + CHUNK; e += 256) {
        int d = dst[e], s = src[e];
        int p = atomicAdd(&cur[d >> 6], 1);
        sp[p] = ((unsigned int)(d & 63) << 24) | (unsigned int)s;
    }
}
// ---- pass D: per-bucket CSR finalize: csrc dense, rowstart/cnt/dinv ----
__launch_bounds__(256)
__global__ void kD2_fin(const unsigned int* __restrict__ sp, const int* __restrict__ bbase,
                        int* __restrict__ csrc, int* __restrict__ rowstart,
                        int* __restrict__ cntg, float* __restrict__ dinv) {
    __shared__ int cnt[64], ofs[64], cur[64];
    __shared__ int tmp[MAXB];
    int b = blockIdx.x, t = threadIdx.x;
    int beg = bbase[b], end = bbase[b + 1], n = end - beg;
    if (t < 64) cnt[t] = 0;
    __syncthreads();
    for (int i = beg + t; i < end; i += 256) atomicAdd(&cnt[sp[i] >> 24], 1);
    __syncthreads();
    if (t == 0) {
        int acc = 0;
        for (int k = 0; k < 64; ++k) { int v = cnt[k]; ofs[k] = acc; cur[k] = acc; acc += v; }
    }
    __syncthreads();
    int node = b * 64 + t;
    if (t < 64 && node < NN) {
        rowstart[node] = beg + ofs[t];
        cntg[node] = cnt[t];
        dinv[node] = rsqrtf((float)(cnt[t] + 1));
    }
    if (n <= MAXB) {
        for (int i = beg + t; i < end; i += 256) {
            unsigned int v = sp[i];
            int p = atomicAdd(&cur[v >> 24], 1);
            tmp[p] = (int)(v & 0xFFFFFFu);
        }
        __syncthreads();
        for (int i = t; i < n; i += 256) csrc[beg + i] = tmp[i];  // dense, full lines
    } else {  // safety fallback
        for (int i = beg + t; i < end; i += 256) {
            unsigned int v = sp[i];
            int p = atomicAdd(&cur[v >> 24], 1);
            csrc[beg + p] = (int)(v & 0xFFFFFFu);
        }
    }
}

// ---- fused GEMM (N x 64) @ (64 x 64), epilogue premult by dinv ----
// 64 rows/block (grid 1563), 4-way split accumulators (ILP).
// MODE 0: Yp = dinv * (X @ W)
// MODE 1: a = relu(bn(X)); side = a; Yp = dinv * (a @ W)
template <int MODE>
__launch_bounds__(256)
__global__ void k_gemm64(const float* __restrict__ X, const float* __restrict__ W,
                         const float* __restrict__ scsh, const float* __restrict__ dinv,
                         float* __restrict__ Yp, float* __restrict__ side) {
    __shared__ float Ws[64 * 64];
    __shared__ float xs[4][64];
    int t = threadIdx.x;
#pragma unroll
    for (int i = 0; i < 16; ++i) Ws[t + 256 * i] = W[t + 256 * i];
    int c = t & 63, rr = t >> 6;
    float scale = 1.f, shift = 0.f;
    if (MODE == 1) { scale = scsh[c]; shift = scsh[64 + c]; }
    int base = blockIdx.x * 64;
    for (int rb = 0; rb < 16; ++rb) {
        int row = base + rb * 4 + rr;
        float v = 0.f;
        if (row < NN) {
            v = X[row * 64 + c];
            if (MODE == 1) {
                v = fmaxf(fmaf(v, scale, shift), 0.f);
                side[row * 64 + c] = v;
            }
        }
        xs[rr][c] = v;
        __syncthreads();
        if (row < NN) {
            float a0 = 0.f, a1 = 0.f, a2 = 0.f, a3 = 0.f;
#pragma unroll
            for (int k = 0; k < 64; k += 4) {
                a0 = fmaf(xs[rr][k],     Ws[k * 64 + c],       a0);
                a1 = fmaf(xs[rr][k + 1], Ws[(k + 1) * 64 + c], a1);
                a2 = fmaf(xs[rr][k + 2], Ws[(k + 2) * 64 + c], a2);
                a3 = fmaf(xs[rr][k + 3], Ws[(k + 3) * 64 + c], a3);
            }
            Yp[row * 64 + c] = dinv[row] * ((a0 + a1) + (a2 + a3));
        }
        __syncthreads();
    }
}

// ---- CSR aggregation: agg[d] = dinv[d]*(Yp[d] + sum Yp[src]); 1 wave/node ----
__launch_bounds__(256)
__global__ void k_agg_csr(const float* __restrict__ Yp, const int* __restrict__ rowstart,
                          const int* __restrict__ cnt, const int* __restrict__ csrc,
                          const float* __restrict__ dinv, float* __restrict__ agg) {
    int wid = (blockIdx.x * blockDim.x + threadIdx.x) >> 6;  // node
    int lane = threadIdx.x & 63;
    if (wid >= NN) return;
    int grp = lane >> 4;  // 0..3: edge slot
    int l16 = lane & 15;  // float4 channel quad
    int beg = rowstart[wid], n = cnt[wid];
    float4 acc = {0.f, 0.f, 0.f, 0.f};
    if (grp == 0) acc = ((const float4*)(Yp + (long)wid * 64))[l16];  // self loop
    int j = grp;
    for (; j + 4 < n; j += 8) {  // 2 edges in flight per lane-group
        int s0 = csrc[beg + j];
        int s1 = csrc[beg + j + 4];
        float4 v0 = ((const float4*)(Yp + (long)s0 * 64))[l16];
        float4 v1 = ((const float4*)(Yp + (long)s1 * 64))[l16];
        acc.x += v0.x + v1.x; acc.y += v0.y + v1.y;
        acc.z += v0.z + v1.z; acc.w += v0.w + v1.w;
    }
    if (j < n) {
        int s = csrc[beg + j];
        float4 v = ((const float4*)(Yp + (long)s * 64))[l16];
        acc.x += v.x; acc.y += v.y; acc.z += v.z; acc.w += v.w;
    }
#pragma unroll
    for (int m = 16; m <= 32; m <<= 1) {
        acc.x += __shfl_xor(acc.x, m);
        acc.y += __shfl_xor(acc.y, m);
        acc.z += __shfl_xor(acc.z, m);
        acc.w += __shfl_xor(acc.w, m);
    }
    if (grp == 0) {
        float d = dinv[wid];
        float4 r = {acc.x * d, acc.y * d, acc.z * d, acc.w * d};
        ((float4*)(agg + (long)wid * 64))[l16] = r;
    }
}

// ---- BatchNorm stats ----
__launch_bounds__(256)
__global__ void k_bn_stats(const float* __restrict__ X, float* __restrict__ stats) {
    __shared__ float sh[512];
    int t = threadIdx.x;
    int c = t & 63, rr = t >> 6;
    float sum = 0.f, sq = 0.f;
    for (int r = blockIdx.x * 4 + rr; r < NN; r += gridDim.x * 4) {
        float v = X[r * 64 + c];
        sum += v;
        sq = fmaf(v, v, sq);
    }
    sh[t] = sum;
    sh[256 + t] = sq;
    __syncthreads();
    if (t < 64) {
        float s = sh[t] + sh[t + 64] + sh[t + 128] + sh[t + 192];
        float q = sh[256 + t] + sh[320 + t] + sh[384 + t] + sh[448 + t];
        atomicAdd(&stats[t], s);
        atomicAdd(&stats[64 + t], q);
    }
}
__global__ void k_bn_final(const float* __restrict__ stats, const float* __restrict__ g,
                           const float* __restrict__ be, float* __restrict__ scsh) {
    int c = threadIdx.x;
    if (c < 64) {
        float mean = stats[c] * (1.0f / NN);
        float var = stats[64 + c] * (1.0f / NN) - mean * mean;
        float sc = g[c] * rsqrtf(var + 1e-5f);
        scsh[c] = sc;
        scsh[64 + c] = be[c] - mean * sc;
    }
}

// ---- final layer GEMM: Tp = dinv * ((relu(bn(X)) + R) @ W2) ----
__launch_bounds__(256)
__global__ void k_gemm_out2(const float* __restrict__ X, const float* __restrict__ scsh,
                            const float* __restrict__ R, const float* __restrict__ W2,
                            const float* __restrict__ dinv, float* __restrict__ Tp) {
    int t = threadIdx.x;
    int lane = t & 63, wv = t >> 6;
    int row = blockIdx.x * 4 + wv;
    if (row >= NN) return;
    float w0 = W2[lane * 2], w1 = W2[lane * 2 + 1];
    float scale = scsh[lane], shift = scsh[64 + lane];
    float v = X[row * 64 + lane];
    v = fmaxf(fmaf(v, scale, shift), 0.f) + R[row * 64 + lane];
    float p0 = v * w0, p1 = v * w1;
#pragma unroll
    for (int s = 32; s; s >>= 1) {
        p0 += __shfl_xor(p0, s);
        p1 += __shfl_xor(p1, s);
    }
    if (lane == 0) {
        float d = dinv[row];
        Tp[row * 2] = d * p0;
        Tp[row * 2 + 1] = d * p1;
    }
}

// ---- final CSR aggregation, 2 channels, 8 lanes/node ----
__launch_bounds__(256)
__global__ void k_out_csr(const float* __restrict__ Tp, const int* __restrict__ rowstart,
                          const int* __restrict__ cnt, const int* __restrict__ csrc,
                          const float* __restrict__ dinv, const float* __restrict__ b2,
                          float* __restrict__ out) {
    int id = blockIdx.x * blockDim.x + threadIdx.x;
    int node = id >> 3, l = id & 7;
    if (node >= NN) return;
    int beg = rowstart[node], n = cnt[node];
    float a0 = 0.f, a1 = 0.f;
    if (l == 0) { a0 = Tp[node * 2]; a1 = Tp[node * 2 + 1]; }  // self loop
    for (int j = l; j < n; j += 8) {
        int s = csrc[beg + j];
        a0 += Tp[s * 2];
        a1 += Tp[s * 2 + 1];
    }
#pragma unroll
    for (int m = 1; m < 8; m <<= 1) {
        a0 += __shfl_xor(a0, m);
        a1 += __shfl_xor(a1, m);
    }
    if (l == 0) {
        float d = dinv[node];
        out[node * 2] = d * a0 + b2[0];
        out[node * 2 + 1] = d * a1 + b2[1];
    }
}

extern "C" void kernel_launch(void* const* d_in, const int* in_sizes, int n_in,
                              void* d_out, int out_size, void* d_ws, size_t ws_size,
                              hipStream_t stream) {
    const float* x   = (const float*)d_in[0];
    const int*   ei  = (const int*)d_in[1];
    const int*   src = ei;
    const int*   dst = ei + NE;
    const float* W0  = (const float*)d_in[2];
    const float* g0  = (const float*)d_in[4];
    const float* be0 = (const float*)d_in[5];
    const float* W1  = (const float*)d_in[6];
    const float* g1  = (const float*)d_in[8];
    const float* be1 = (const float*)d_in[9];
    const float* W2  = (const float*)d_in[10];
    const float* b2  = (const float*)d_in[11];
    float* out = (float*)d_out;

    int*   H      = (int*)d_ws;                    // NBUCK*NBLK ints (1.6MB)
    int*   bsum   = H + NBUCK * NBLK;              // pad 2048
    int*   bbase  = bsum + 2048;                   // pad 2048 (NBUCK+1 used)
    unsigned int* sp = (unsigned int*)(bbase + 2048);  // NE packed
    int*   csrc   = (int*)(sp + NE);               // NE
    int*   rowstart = csrc + NE;                   // N
    int*   cntg   = rowstart + NN;                 // N
    float* dinv   = (float*)(cntg + NN);           // N
    float* A      = dinv + NN;                     // N*64 (Yp)
    float* B      = A + NN * 64;                   // N*64 (agg)
    float* C      = B + NN * 64;                   // N*64 (hres)
    float* Tp     = C + NN * 64;                   // N*2
    float* stats0 = Tp + NN * 2;                   // 128
    float* stats1 = stats0 + 128;                  // 128
    float* scsh0  = stats1 + 128;                  // 128
    float* scsh1  = scsh0 + 128;                   // 128

    hipMemsetAsync(stats0, 0, 256 * sizeof(float), stream);

    // CSR build: bucket sort by dst>>6, then per-bucket LDS finalize
    kA_hist<<<NBLK, 256, 0, stream>>>(dst, H);
    kB1<<<NBUCK, 256, 0, stream>>>(H, bsum);
    kB2<<<1, 256, 0, stream>>>(bsum, bbase);
    kB3<<<NBUCK, 256, 0, stream>>>(H, bbase);
    kC_scatter<<<NBLK, 256, 0, stream>>>(src, dst, H, sp);
    kD2_fin<<<NBUCK, 256, 0, stream>>>(sp, bbase, csrc, rowstart, cntg, dinv);

    int gemmGrid = (NN + 63) / 64;   // 1563 blocks, 64 rows each
    int aggGrid  = (NN * 64) / 256;  // one wave per node, exact

    // layer 0
    k_gemm64<0><<<gemmGrid, 256, 0, stream>>>(x, W0, nullptr, dinv, A, nullptr);
    k_agg_csr<<<aggGrid, 256, 0, stream>>>(A, rowstart, cntg, csrc, dinv, B);
    k_bn_stats<<<256, 256, 0, stream>>>(B, stats0);
    k_bn_final<<<1, 64, 0, stream>>>(stats0, g0, be0, scsh0);

    // layer 1
    k_gemm64<1><<<gemmGrid, 256, 0, stream>>>(B, W1, scsh0, dinv, A, C);
    k_agg_csr<<<aggGrid, 256, 0, stream>>>(A, rowstart, cntg, csrc, dinv, B);
    k_bn_stats<<<256, 256, 0, stream>>>(B, stats1);
    k_bn_final<<<1, 64, 0, stream>>>(stats1, g1, be1, scsh1);

    // layer 2
    k_gemm_out2<<<(NN + 3) / 4, 256, 0, stream>>>(B, scsh1, C, W2, dinv, Tp);
    k_out_csr<<<(NN * 8 + 255) / 256, 256, 0, stream>>>(Tp, rowstart, cntg, csrc, dinv, b2, out);
}

// Round 9
// 461.234 us; speedup vs baseline: 3.5054x; 1.0619x over previous
//
#include <hip/hip_runtime.h>

// ResGCN: 3x GCNConv(+BN+ReLU, residual), N=100k, E=1.6M.
// R9: R7 + bf16 storage of the gathered feature buffer Yp (halves the
// agg gather traffic: working set 25.6->12.8MB, per-edge 256->128B), and
// bn_final folded into the consuming GEMMs (scale/shift derived per block).
// R8 counters: k_agg_csr 63us, FETCH 192MB = L2-miss gather traffic -> shrink bytes.
// b0/b1 skipped (cancelled by BN mean-sub).

#define NN 100000
#define NE 1600000
#define NBUCK 1563        // ceil(NN/64); bucket = dst >> 6
#define NBLK 256          // sort blocks
#define CHUNK 6250        // NE / NBLK exact
#define MAXB 2048         // LDS finalize capacity (avg bucket = 1024)

typedef unsigned short ushort_t;

__device__ __forceinline__ ushort_t f2bf(float f) {  // RTNE
    unsigned u = __float_as_uint(f);
    unsigned r = u + 0x7FFFu + ((u >> 16) & 1u);
    return (ushort_t)(r >> 16);
}
__device__ __forceinline__ float bf2f(ushort_t h) {
    return __uint_as_float(((unsigned)h) << 16);
}

// ---- pass A: per-block bucket histogram (transposed: H[bucket*NBLK + blk]) ----
__launch_bounds__(256)
__global__ void kA_hist(const int* __restrict__ dst, int* __restrict__ H) {
    __shared__ int h[NBUCK];
    int t = threadIdx.x, blk = blockIdx.x;
    for (int b = t; b < NBUCK; b += 256) h[b] = 0;
    __syncthreads();
    int e0 = blk * CHUNK;
    for (int e = e0 + t; e < e0 + CHUNK; e += 256) atomicAdd(&h[dst[e] >> 6], 1);
    __syncthreads();
    for (int b = t; b < NBUCK; b += 256) H[b * NBLK + blk] = h[b];
}
// ---- pass B1: bucket totals ----
__launch_bounds__(256)
__global__ void kB1(const int* __restrict__ H, int* __restrict__ bsum) {
    __shared__ int sh[256];
    int b = blockIdx.x, t = threadIdx.x;
    sh[t] = H[b * NBLK + t];
    __syncthreads();
    for (int s = 128; s; s >>= 1) {
        if (t < s) sh[t] += sh[t + s];
        __syncthreads();
    }
    if (t == 0) bsum[b] = sh[0];
}
// ---- pass B2: exclusive scan of bucket totals -> bbase[0..NBUCK] ----
__global__ void kB2(const int* __restrict__ bsum, int* __restrict__ bbase) {
    __shared__ int sh[NBUCK];
    int t = threadIdx.x;
    for (int b = t; b < NBUCK; b += 256) sh[b] = bsum[b];
    __syncthreads();
    if (t == 0) {
        int acc = 0;
        for (int b = 0; b < NBUCK; ++b) { int v = sh[b]; sh[b] = acc; acc += v; }
        bbase[NBUCK] = acc;  // == NE
    }
    __syncthreads();
    for (int b = t; b < NBUCK; b += 256) bbase[b] = sh[b];
}
// ---- pass B3: per-(bucket,blk) offsets, in place over H ----
__launch_bounds__(256)
__global__ void kB3(int* __restrict__ H, const int* __restrict__ bbase) {
    __shared__ int sh[256];
    int b = blockIdx.x, t = threadIdx.x;
    sh[t] = H[b * NBLK + t];
    __syncthreads();
    if (t == 0) {
        int acc = bbase[b];
        for (int i = 0; i < 256; ++i) { int v = sh[i]; sh[i] = acc; acc += v; }
    }
    __syncthreads();
    H[b * NBLK + t] = sh[t];
}
// ---- pass C: scatter packed (node6|src24) into bucket order ----
__launch_bounds__(256)
__global__ void kC_scatter(const int* __restrict__ src, const int* __restrict__ dst,
                           const int* __restrict__ O, unsigned int* __restrict__ sp) {
    __shared__ int cur[NBUCK];
    int t = threadIdx.x, blk = blockIdx.x;
    for (int b = t; b < NBUCK; b += 256) cur[b] = O[b * NBLK + blk];
    __syncthreads();
    int e0 = blk * CHUNK;
    for (int e = e0 + t; e < e0 + CHUNK; e += 256) {
        int d = dst[e], s = src[e];
        int p = atomicAdd(&cur[d >> 6], 1);
        sp[p] = ((unsigned int)(d & 63) << 24) | (unsigned int)s;
    }
}
// ---- pass D: per-bucket CSR finalize: csrc dense, rowstart/cnt/dinv ----
__launch_bounds__(256)
__global__ void kD2_fin(const unsigned int* __restrict__ sp, const int* __restrict__ bbase,
                        int* __restrict__ csrc, int* __restrict__ rowstart,
                        int* __restrict__ cntg, float* __restrict__ dinv) {
    __shared__ int cnt[64], ofs[64], cur[64];
    __shared__ int tmp[MAXB];
    int b = blockIdx.x, t = threadIdx.x;
    int beg = bbase[b], end = bbase[b + 1], n = end - beg;
    if (t < 64) cnt[t] = 0;
    __syncthreads();
    for (int i = beg + t; i < end; i += 256) atomicAdd(&cnt[sp[i] >> 24], 1);
    __syncthreads();
    if (t == 0) {
        int acc = 0;
        for (int k = 0; k < 64; ++k) { int v = cnt[k]; ofs[k] = acc; cur[k] = acc; acc += v; }
    }
    __syncthreads();
    int node = b * 64 + t;
    if (t < 64 && node < NN) {
        rowstart[node] = beg + ofs[t];
        cntg[node] = cnt[t];
        dinv[node] = rsqrtf((float)(cnt[t] + 1));
    }
    if (n <= MAXB) {
        for (int i = beg + t; i < end; i += 256) {
            unsigned int v = sp[i];
            int p = atomicAdd(&cur[v >> 24], 1);
            tmp[p] = (int)(v & 0xFFFFFFu);
        }
        __syncthreads();
        for (int i = t; i < n; i += 256) csrc[beg + i] = tmp[i];  // dense, full lines
    } else {  // safety fallback
        for (int i = beg + t; i < end; i += 256) {
            unsigned int v = sp[i];
            int p = atomicAdd(&cur[v >> 24], 1);
            csrc[beg + p] = (int)(v & 0xFFFFFFu);
        }
    }
}

// ---- fused GEMM (N x 64) @ (64 x 64), epilogue premult by dinv, bf16 out ----
// 64 rows/block (grid 1563), 4-way split accumulators.
// MODE 0: Yb = bf16(dinv * (X @ W))
// MODE 1: scsh from stats/g/be; a = relu(bn(X)); side = a; Yb = bf16(dinv*(a@W))
template <int MODE>
__launch_bounds__(256)
__global__ void k_gemm64(const float* __restrict__ X, const float* __restrict__ W,
                         const float* __restrict__ stats, const float* __restrict__ g,
                         const float* __restrict__ be, const float* __restrict__ dinv,
                         ushort_t* __restrict__ Yb, float* __restrict__ side) {
    __shared__ float Ws[64 * 64];
    __shared__ float xs[4][64];
    int t = threadIdx.x;
#pragma unroll
    for (int i = 0; i < 16; ++i) Ws[t + 256 * i] = W[t + 256 * i];
    int c = t & 63, rr = t >> 6;
    float scale = 1.f, shift = 0.f;
    if (MODE == 1) {  // bn_final folded in: derive scale/shift from raw stats
        float mean = stats[c] * (1.0f / NN);
        float var = stats[64 + c] * (1.0f / NN) - mean * mean;
        scale = g[c] * rsqrtf(var + 1e-5f);
        shift = be[c] - mean * scale;
    }
    int base = blockIdx.x * 64;
    for (int rb = 0; rb < 16; ++rb) {
        int row = base + rb * 4 + rr;
        float v = 0.f;
        if (row < NN) {
            v = X[row * 64 + c];
            if (MODE == 1) {
                v = fmaxf(fmaf(v, scale, shift), 0.f);
                side[row * 64 + c] = v;
            }
        }
        xs[rr][c] = v;
        __syncthreads();
        if (row < NN) {
            float a0 = 0.f, a1 = 0.f, a2 = 0.f, a3 = 0.f;
#pragma unroll
            for (int k = 0; k < 64; k += 4) {
                a0 = fmaf(xs[rr][k],     Ws[k * 64 + c],       a0);
                a1 = fmaf(xs[rr][k + 1], Ws[(k + 1) * 64 + c], a1);
                a2 = fmaf(xs[rr][k + 2], Ws[(k + 2) * 64 + c], a2);
                a3 = fmaf(xs[rr][k + 3], Ws[(k + 3) * 64 + c], a3);
            }
            Yb[row * 64 + c] = f2bf(dinv[row] * ((a0 + a1) + (a2 + a3)));
        }
        __syncthreads();
    }
}

// ---- CSR aggregation (bf16 gather): agg[d] = dinv[d]*(Yb[d] + sum Yb[src]) ----
__launch_bounds__(256)
__global__ void k_agg_csr(const ushort_t* __restrict__ Yb, const int* __restrict__ rowstart,
                          const int* __restrict__ cnt, const int* __restrict__ csrc,
                          const float* __restrict__ dinv, float* __restrict__ agg) {
    int wid = (blockIdx.x * blockDim.x + threadIdx.x) >> 6;  // node
    int lane = threadIdx.x & 63;
    if (wid >= NN) return;
    int grp = lane >> 4;  // 0..3: edge slot
    int l16 = lane & 15;  // 4-channel quad
    int beg = rowstart[wid], n = cnt[wid];
    float4 acc = {0.f, 0.f, 0.f, 0.f};
    if (grp == 0) {  // self loop
        ushort4 v = ((const ushort4*)(Yb + (long)wid * 64))[l16];
        acc.x = bf2f(v.x); acc.y = bf2f(v.y); acc.z = bf2f(v.z); acc.w = bf2f(v.w);
    }
    int j = grp;
    for (; j + 4 < n; j += 8) {  // 2 edges in flight per lane-group
        int s0 = csrc[beg + j];
        int s1 = csrc[beg + j + 4];
        ushort4 v0 = ((const ushort4*)(Yb + (long)s0 * 64))[l16];
        ushort4 v1 = ((const ushort4*)(Yb + (long)s1 * 64))[l16];
        acc.x += bf2f(v0.x) + bf2f(v1.x);
        acc.y += bf2f(v0.y) + bf2f(v1.y);
        acc.z += bf2f(v0.z) + bf2f(v1.z);
        acc.w += bf2f(v0.w) + bf2f(v1.w);
    }
    if (j < n) {
        int s = csrc[beg + j];
        ushort4 v = ((const ushort4*)(Yb + (long)s * 64))[l16];
        acc.x += bf2f(v.x); acc.y += bf2f(v.y); acc.z += bf2f(v.z); acc.w += bf2f(v.w);
    }
#pragma unroll
    for (int m = 16; m <= 32; m <<= 1) {
        acc.x += __shfl_xor(acc.x, m);
        acc.y += __shfl_xor(acc.y, m);
        acc.z += __shfl_xor(acc.z, m);
        acc.w += __shfl_xor(acc.w, m);
    }
    if (grp == 0) {
        float d = dinv[wid];
        float4 r = {acc.x * d, acc.y * d, acc.z * d, acc.w * d};
        ((float4*)(agg + (long)wid * 64))[l16] = r;
    }
}

// ---- BatchNorm stats (raw sums; finalize folded into consumers) ----
__launch_bounds__(256)
__global__ void k_bn_stats(const float* __restrict__ X, float* __restrict__ stats) {
    __shared__ float sh[512];
    int t = threadIdx.x;
    int c = t & 63, rr = t >> 6;
    float sum = 0.f, sq = 0.f;
    for (int r = blockIdx.x * 4 + rr; r < NN; r += gridDim.x * 4) {
        float v = X[r * 64 + c];
        sum += v;
        sq = fmaf(v, v, sq);
    }
    sh[t] = sum;
    sh[256 + t] = sq;
    __syncthreads();
    if (t < 64) {
        float s = sh[t] + sh[t + 64] + sh[t + 128] + sh[t + 192];
        float q = sh[256 + t] + sh[320 + t] + sh[384 + t] + sh[448 + t];
        atomicAdd(&stats[t], s);
        atomicAdd(&stats[64 + t], q);
    }
}

// ---- final layer GEMM: Tp = dinv * ((relu(bn(X)) + R) @ W2) ----
__launch_bounds__(256)
__global__ void k_gemm_out2(const float* __restrict__ X, const float* __restrict__ stats,
                            const float* __restrict__ g, const float* __restrict__ be,
                            const float* __restrict__ R, const float* __restrict__ W2,
                            const float* __restrict__ dinv, float* __restrict__ Tp) {
    int t = threadIdx.x;
    int lane = t & 63, wv = t >> 6;
    int row = blockIdx.x * 4 + wv;
    if (row >= NN) return;
    float mean = stats[lane] * (1.0f / NN);
    float var = stats[64 + lane] * (1.0f / NN) - mean * mean;
    float scale = g[lane] * rsqrtf(var + 1e-5f);
    float shift = be[lane] - mean * scale;
    float w0 = W2[lane * 2], w1 = W2[lane * 2 + 1];
    float v = X[row * 64 + lane];
    v = fmaxf(fmaf(v, scale, shift), 0.f) + R[row * 64 + lane];
    float p0 = v * w0, p1 = v * w1;
#pragma unroll
    for (int s = 32; s; s >>= 1) {
        p0 += __shfl_xor(p0, s);
        p1 += __shfl_xor(p1, s);
    }
    if (lane == 0) {
        float d = dinv[row];
        Tp[row * 2] = d * p0;
        Tp[row * 2 + 1] = d * p1;
    }
}

// ---- final CSR aggregation, 2 channels, 8 lanes/node ----
__launch_bounds__(256)
__global__ void k_out_csr(const float* __restrict__ Tp, const int* __restrict__ rowstart,
                          const int* __restrict__ cnt, const int* __restrict__ csrc,
                          const float* __restrict__ dinv, const float* __restrict__ b2,
                          float* __restrict__ out) {
    int id = blockIdx.x * blockDim.x + threadIdx.x;
    int node = id >> 3, l = id & 7;
    if (node >= NN) return;
    int beg = rowstart[node], n = cnt[node];
    float a0 = 0.f, a1 = 0.f;
    if (l == 0) { a0 = Tp[node * 2]; a1 = Tp[node * 2 + 1]; }  // self loop
    for (int j = l; j < n; j += 8) {
        int s = csrc[beg + j];
        a0 += Tp[s * 2];
        a1 += Tp[s * 2 + 1];
    }
#pragma unroll
    for (int m = 1; m < 8; m <<= 1) {
        a0 += __shfl_xor(a0, m);
        a1 += __shfl_xor(a1, m);
    }
    if (l == 0) {
        float d = dinv[node];
        out[node * 2] = d * a0 + b2[0];
        out[node * 2 + 1] = d * a1 + b2[1];
    }
}

extern "C" void kernel_launch(void* const* d_in, const int* in_sizes, int n_in,
                              void* d_out, int out_size, void* d_ws, size_t ws_size,
                              hipStream_t stream) {
    const float* x   = (const float*)d_in[0];
    const int*   ei  = (const int*)d_in[1];
    const int*   src = ei;
    const int*   dst = ei + NE;
    const float* W0  = (const float*)d_in[2];
    const float* g0  = (const float*)d_in[4];
    const float* be0 = (const float*)d_in[5];
    const float* W1  = (const float*)d_in[6];
    const float* g1  = (const float*)d_in[8];
    const float* be1 = (const float*)d_in[9];
    const float* W2  = (const float*)d_in[10];
    const float* b2  = (const float*)d_in[11];
    float* out = (float*)d_out;

    int*   H      = (int*)d_ws;                    // NBUCK*NBLK ints (1.6MB)
    int*   bsum   = H + NBUCK * NBLK;              // pad 2048
    int*   bbase  = bsum + 2048;                   // pad 2048 (NBUCK+1 used)
    unsigned int* sp = (unsigned int*)(bbase + 2048);  // NE packed
    int*   csrc   = (int*)(sp + NE);               // NE
    int*   rowstart = csrc + NE;                   // N
    int*   cntg   = rowstart + NN;                 // N
    float* dinv   = (float*)(cntg + NN);           // N
    ushort_t* Ab  = (ushort_t*)(dinv + NN);        // N*64 bf16 (Yp)
    float* B      = (float*)(Ab + NN * 64);        // N*64 fp32 (agg)
    float* C      = B + NN * 64;                   // N*64 (hres)
    float* Tp     = C + NN * 64;                   // N*2
    float* stats0 = Tp + NN * 2;                   // 128
    float* stats1 = stats0 + 128;                  // 128

    hipMemsetAsync(stats0, 0, 256 * sizeof(float), stream);

    // CSR build: bucket sort by dst>>6, then per-bucket LDS finalize
    kA_hist<<<NBLK, 256, 0, stream>>>(dst, H);
    kB1<<<NBUCK, 256, 0, stream>>>(H, bsum);
    kB2<<<1, 256, 0, stream>>>(bsum, bbase);
    kB3<<<NBUCK, 256, 0, stream>>>(H, bbase);
    kC_scatter<<<NBLK, 256, 0, stream>>>(src, dst, H, sp);
    kD2_fin<<<NBUCK, 256, 0, stream>>>(sp, bbase, csrc, rowstart, cntg, dinv);

    int gemmGrid = (NN + 63) / 64;   // 1563 blocks, 64 rows each
    int aggGrid  = (NN * 64) / 256;  // one wave per node, exact

    // layer 0
    k_gemm64<0><<<gemmGrid, 256, 0, stream>>>(x, W0, nullptr, nullptr, nullptr, dinv, Ab, nullptr);
    k_agg_csr<<<aggGrid, 256, 0, stream>>>(Ab, rowstart, cntg, csrc, dinv, B);
    k_bn_stats<<<256, 256, 0, stream>>>(B, stats0);

    // layer 1 (bn_final folded into gemm)
    k_gemm64<1><<<gemmGrid, 256, 0, stream>>>(B, W1, stats0, g0, be0, dinv, Ab, C);
    k_agg_csr<<<aggGrid, 256, 0, stream>>>(Ab, rowstart, cntg, csrc, dinv, B);
    k_bn_stats<<<256, 256, 0, stream>>>(B, stats1);

    // layer 2 (bn_final folded into gemm_out2)
    k_gemm_out2<<<(NN + 3) / 4, 256, 0, stream>>>(B, stats1, g1, be1, C, W2, dinv, Tp);
    k_out_csr<<<(NN * 8 + 255) / 256, 256, 0, stream>>>(Tp, rowstart, cntg, csrc, dinv, b2, out);
}

// Round 10
// 419.881 us; speedup vs baseline: 3.8506x; 1.0985x over previous
//
#include <hip/hip_runtime.h>

// ResGCN: 3x GCNConv(+BN+ReLU, residual), N=100k, E=1.6M.
// R10: R9 + gemm64 LDS-pressure fix. R9 counters: gemm64 58us, VALUBusy 38%,
// HBM 6% -> LDS-issue-bound (1 ds_read_b32 of W per FMA). Fix: W column in 64
// VGPRs (fixed per thread, loaded once from L2), xs via ds_read_b128 broadcast
// (16/row not 64), and NO barriers (xs[rr] is wave-private -> the two
// __syncthreads per row-group were unnecessary). b0/b1 skipped (BN mean-sub).

#define NN 100000
#define NE 1600000
#define NBUCK 1563        // ceil(NN/64); bucket = dst >> 6
#define NBLK 256          // sort blocks
#define CHUNK 6250        // NE / NBLK exact
#define MAXB 2048         // LDS finalize capacity (avg bucket = 1024)

typedef unsigned short ushort_t;

__device__ __forceinline__ ushort_t f2bf(float f) {  // RTNE
    unsigned u = __float_as_uint(f);
    unsigned r = u + 0x7FFFu + ((u >> 16) & 1u);
    return (ushort_t)(r >> 16);
}
__device__ __forceinline__ float bf2f(ushort_t h) {
    return __uint_as_float(((unsigned)h) << 16);
}

// ---- pass A: per-block bucket histogram (transposed: H[bucket*NBLK + blk]) ----
__launch_bounds__(256)
__global__ void kA_hist(const int* __restrict__ dst, int* __restrict__ H) {
    __shared__ int h[NBUCK];
    int t = threadIdx.x, blk = blockIdx.x;
    for (int b = t; b < NBUCK; b += 256) h[b] = 0;
    __syncthreads();
    int e0 = blk * CHUNK;
    for (int e = e0 + t; e < e0 + CHUNK; e += 256) atomicAdd(&h[dst[e] >> 6], 1);
    __syncthreads();
    for (int b = t; b < NBUCK; b += 256) H[b * NBLK + blk] = h[b];
}
// ---- pass B1: bucket totals ----
__launch_bounds__(256)
__global__ void kB1(const int* __restrict__ H, int* __restrict__ bsum) {
    __shared__ int sh[256];
    int b = blockIdx.x, t = threadIdx.x;
    sh[t] = H[b * NBLK + t];
    __syncthreads();
    for (int s = 128; s; s >>= 1) {
        if (t < s) sh[t] += sh[t + s];
        __syncthreads();
    }
    if (t == 0) bsum[b] = sh[0];
}
// ---- pass B2: exclusive scan of bucket totals -> bbase[0..NBUCK] ----
__global__ void kB2(const int* __restrict__ bsum, int* __restrict__ bbase) {
    __shared__ int sh[NBUCK];
    int t = threadIdx.x;
    for (int b = t; b < NBUCK; b += 256) sh[b] = bsum[b];
    __syncthreads();
    if (t == 0) {
        int acc = 0;
        for (int b = 0; b < NBUCK; ++b) { int v = sh[b]; sh[b] = acc; acc += v; }
        bbase[NBUCK] = acc;  // == NE
    }
    __syncthreads();
    for (int b = t; b < NBUCK; b += 256) bbase[b] = sh[b];
}
// ---- pass B3: per-(bucket,blk) offsets, in place over H ----
__launch_bounds__(256)
__global__ void kB3(int* __restrict__ H, const int* __restrict__ bbase) {
    __shared__ int sh[256];
    int b = blockIdx.x, t = threadIdx.x;
    sh[t] = H[b * NBLK + t];
    __syncthreads();
    if (t == 0) {
        int acc = bbase[b];
        for (int i = 0; i < 256; ++i) { int v = sh[i]; sh[i] = acc; acc += v; }
    }
    __syncthreads();
    H[b * NBLK + t] = sh[t];
}
// ---- pass C: scatter packed (node6|src24) into bucket order ----
__launch_bounds__(256)
__global__ void kC_scatter(const int* __restrict__ src, const int* __restrict__ dst,
                           const int* __restrict__ O, unsigned int* __restrict__ sp) {
    __shared__ int cur[NBUCK];
    int t = threadIdx.x, blk = blockIdx.x;
    for (int b = t; b < NBUCK; b += 256) cur[b] = O[b * NBLK + blk];
    __syncthreads();
    int e0 = blk * CHUNK;
    for (int e = e0 + t; e < e0 + CHUNK; e += 256) {
        int d = dst[e], s = src[e];
        int p = atomicAdd(&cur[d >> 6], 1);
        sp[p] = ((unsigned int)(d & 63) << 24) | (unsigned int)s;
    }
}
// ---- pass D: per-bucket CSR finalize: csrc dense, rowstart/cnt/dinv ----
__launch_bounds__(256)
__global__ void kD2_fin(const unsigned int* __restrict__ sp, const int* __restrict__ bbase,
                        int* __restrict__ csrc, int* __restrict__ rowstart,
                        int* __restrict__ cntg, float* __restrict__ dinv) {
    __shared__ int cnt[64], ofs[64], cur[64];
    __shared__ int tmp[MAXB];
    int b = blockIdx.x, t = threadIdx.x;
    int beg = bbase[b], end = bbase[b + 1], n = end - beg;
    if (t < 64) cnt[t] = 0;
    __syncthreads();
    for (int i = beg + t; i < end; i += 256) atomicAdd(&cnt[sp[i] >> 24], 1);
    __syncthreads();
    if (t == 0) {
        int acc = 0;
        for (int k = 0; k < 64; ++k) { int v = cnt[k]; ofs[k] = acc; cur[k] = acc; acc += v; }
    }
    __syncthreads();
    int node = b * 64 + t;
    if (t < 64 && node < NN) {
        rowstart[node] = beg + ofs[t];
        cntg[node] = cnt[t];
        dinv[node] = rsqrtf((float)(cnt[t] + 1));
    }
    if (n <= MAXB) {
        for (int i = beg + t; i < end; i += 256) {
            unsigned int v = sp[i];
            int p = atomicAdd(&cur[v >> 24], 1);
            tmp[p] = (int)(v & 0xFFFFFFu);
        }
        __syncthreads();
        for (int i = t; i < n; i += 256) csrc[beg + i] = tmp[i];  // dense, full lines
    } else {  // safety fallback
        for (int i = beg + t; i < end; i += 256) {
            unsigned int v = sp[i];
            int p = atomicAdd(&cur[v >> 24], 1);
            csrc[beg + p] = (int)(v & 0xFFFFFFu);
        }
    }
}

// ---- fused GEMM (N x 64) @ (64 x 64): W column in VGPRs, xs b128 broadcast ----
// 64 rows/block (grid 1563). No barriers: xs[rr] is wave-private.
// MODE 0: Yb = bf16(dinv * (X @ W))
// MODE 1: bn folded (stats/g/be); a = relu(bn(X)); side = a; Yb = bf16(dinv*(a@W))
template <int MODE>
__launch_bounds__(256, 4)
__global__ void k_gemm64(const float* __restrict__ X, const float* __restrict__ W,
                         const float* __restrict__ stats, const float* __restrict__ g,
                         const float* __restrict__ be, const float* __restrict__ dinv,
                         ushort_t* __restrict__ Yb, float* __restrict__ side) {
    __shared__ float xs[4][68];  // per-wave row staging (transpose medium)
    int t = threadIdx.x;
    int c = t & 63, rr = t >> 6;
    float w[64];
#pragma unroll
    for (int k = 0; k < 64; ++k) w[k] = W[k * 64 + c];  // coalesced; L2-resident
    float scale = 1.f, shift = 0.f;
    if (MODE == 1) {  // bn_final folded in
        float mean = stats[c] * (1.0f / NN);
        float var = stats[64 + c] * (1.0f / NN) - mean * mean;
        scale = g[c] * rsqrtf(var + 1e-5f);
        shift = be[c] - mean * scale;
    }
    int base = blockIdx.x * 64;
#pragma unroll 2
    for (int rb = 0; rb < 16; ++rb) {
        int row = base + rb * 4 + rr;
        if (row >= NN) continue;
        float v = X[row * 64 + c];
        if (MODE == 1) {
            v = fmaxf(fmaf(v, scale, shift), 0.f);
            side[row * 64 + c] = v;
        }
        xs[rr][c] = v;  // wave-private: no barrier needed (lgkmcnt ordering)
        const float4* xp = (const float4*)xs[rr];
        float a0 = 0.f, a1 = 0.f, a2 = 0.f, a3 = 0.f;
#pragma unroll
        for (int k4 = 0; k4 < 16; ++k4) {
            float4 xv = xp[k4];  // b128 broadcast (same addr across lanes)
            a0 = fmaf(xv.x, w[k4 * 4 + 0], a0);
            a1 = fmaf(xv.y, w[k4 * 4 + 1], a1);
            a2 = fmaf(xv.z, w[k4 * 4 + 2], a2);
            a3 = fmaf(xv.w, w[k4 * 4 + 3], a3);
        }
        Yb[row * 64 + c] = f2bf(dinv[row] * ((a0 + a1) + (a2 + a3)));
    }
}

// ---- CSR aggregation (bf16 gather): agg[d] = dinv[d]*(Yb[d] + sum Yb[src]) ----
__launch_bounds__(256)
__global__ void k_agg_csr(const ushort_t* __restrict__ Yb, const int* __restrict__ rowstart,
                          const int* __restrict__ cnt, const int* __restrict__ csrc,
                          const float* __restrict__ dinv, float* __restrict__ agg) {
    int wid = (blockIdx.x * blockDim.x + threadIdx.x) >> 6;  // node
    int lane = threadIdx.x & 63;
    if (wid >= NN) return;
    int grp = lane >> 4;  // 0..3: edge slot
    int l16 = lane & 15;  // 4-channel quad
    int beg = rowstart[wid], n = cnt[wid];
    float4 acc = {0.f, 0.f, 0.f, 0.f};
    if (grp == 0) {  // self loop
        ushort4 v = ((const ushort4*)(Yb + (long)wid * 64))[l16];
        acc.x = bf2f(v.x); acc.y = bf2f(v.y); acc.z = bf2f(v.z); acc.w = bf2f(v.w);
    }
    int j = grp;
    for (; j + 4 < n; j += 8) {  // 2 edges in flight per lane-group
        int s0 = csrc[beg + j];
        int s1 = csrc[beg + j + 4];
        ushort4 v0 = ((const ushort4*)(Yb + (long)s0 * 64))[l16];
        ushort4 v1 = ((const ushort4*)(Yb + (long)s1 * 64))[l16];
        acc.x += bf2f(v0.x) + bf2f(v1.x);
        acc.y += bf2f(v0.y) + bf2f(v1.y);
        acc.z += bf2f(v0.z) + bf2f(v1.z);
        acc.w += bf2f(v0.w) + bf2f(v1.w);
    }
    if (j < n) {
        int s = csrc[beg + j];
        ushort4 v = ((const ushort4*)(Yb + (long)s * 64))[l16];
        acc.x += bf2f(v.x); acc.y += bf2f(v.y); acc.z += bf2f(v.z); acc.w += bf2f(v.w);
    }
#pragma unroll
    for (int m = 16; m <= 32; m <<= 1) {
        acc.x += __shfl_xor(acc.x, m);
        acc.y += __shfl_xor(acc.y, m);
        acc.z += __shfl_xor(acc.z, m);
        acc.w += __shfl_xor(acc.w, m);
    }
    if (grp == 0) {
        float d = dinv[wid];
        float4 r = {acc.x * d, acc.y * d, acc.z * d, acc.w * d};
        ((float4*)(agg + (long)wid * 64))[l16] = r;
    }
}

// ---- BatchNorm stats (raw sums; finalize folded into consumers) ----
__launch_bounds__(256)
__global__ void k_bn_stats(const float* __restrict__ X, float* __restrict__ stats) {
    __shared__ float sh[512];
    int t = threadIdx.x;
    int c = t & 63, rr = t >> 6;
    float sum = 0.f, sq = 0.f;
    for (int r = blockIdx.x * 4 + rr; r < NN; r += gridDim.x * 4) {
        float v = X[r * 64 + c];
        sum += v;
        sq = fmaf(v, v, sq);
    }
    sh[t] = sum;
    sh[256 + t] = sq;
    __syncthreads();
    if (t < 64) {
        float s = sh[t] + sh[t + 64] + sh[t + 128] + sh[t + 192];
        float q = sh[256 + t] + sh[320 + t] + sh[384 + t] + sh[448 + t];
        atomicAdd(&stats[t], s);
        atomicAdd(&stats[64 + t], q);
    }
}

// ---- final layer GEMM: Tp = dinv * ((relu(bn(X)) + R) @ W2) ----
__launch_bounds__(256)
__global__ void k_gemm_out2(const float* __restrict__ X, const float* __restrict__ stats,
                            const float* __restrict__ g, const float* __restrict__ be,
                            const float* __restrict__ R, const float* __restrict__ W2,
                            const float* __restrict__ dinv, float* __restrict__ Tp) {
    int t = threadIdx.x;
    int lane = t & 63, wv = t >> 6;
    int row = blockIdx.x * 4 + wv;
    if (row >= NN) return;
    float mean = stats[lane] * (1.0f / NN);
    float var = stats[64 + lane] * (1.0f / NN) - mean * mean;
    float scale = g[lane] * rsqrtf(var + 1e-5f);
    float shift = be[lane] - mean * scale;
    float w0 = W2[lane * 2], w1 = W2[lane * 2 + 1];
    float v = X[row * 64 + lane];
    v = fmaxf(fmaf(v, scale, shift), 0.f) + R[row * 64 + lane];
    float p0 = v * w0, p1 = v * w1;
#pragma unroll
    for (int s = 32; s; s >>= 1) {
        p0 += __shfl_xor(p0, s);
        p1 += __shfl_xor(p1, s);
    }
    if (lane == 0) {
        float d = dinv[row];
        Tp[row * 2] = d * p0;
        Tp[row * 2 + 1] = d * p1;
    }
}

// ---- final CSR aggregation, 2 channels, 8 lanes/node ----
__launch_bounds__(256)
__global__ void k_out_csr(const float* __restrict__ Tp, const int* __restrict__ rowstart,
                          const int* __restrict__ cnt, const int* __restrict__ csrc,
                          const float* __restrict__ dinv, const float* __restrict__ b2,
                          float* __restrict__ out) {
    int id = blockIdx.x * blockDim.x + threadIdx.x;
    int node = id >> 3, l = id & 7;
    if (node >= NN) return;
    int beg = rowstart[node], n = cnt[node];
    float a0 = 0.f, a1 = 0.f;
    if (l == 0) { a0 = Tp[node * 2]; a1 = Tp[node * 2 + 1]; }  // self loop
    for (int j = l; j < n; j += 8) {
        int s = csrc[beg + j];
        a0 += Tp[s * 2];
        a1 += Tp[s * 2 + 1];
    }
#pragma unroll
    for (int m = 1; m < 8; m <<= 1) {
        a0 += __shfl_xor(a0, m);
        a1 += __shfl_xor(a1, m);
    }
    if (l == 0) {
        float d = dinv[node];
        out[node * 2] = d * a0 + b2[0];
        out[node * 2 + 1] = d * a1 + b2[1];
    }
}

extern "C" void kernel_launch(void* const* d_in, const int* in_sizes, int n_in,
                              void* d_out, int out_size, void* d_ws, size_t ws_size,
                              hipStream_t stream) {
    const float* x   = (const float*)d_in[0];
    const int*   ei  = (const int*)d_in[1];
    const int*   src = ei;
    const int*   dst = ei + NE;
    const float* W0  = (const float*)d_in[2];
    const float* g0  = (const float*)d_in[4];
    const float* be0 = (const float*)d_in[5];
    const float* W1  = (const float*)d_in[6];
    const float* g1  = (const float*)d_in[8];
    const float* be1 = (const float*)d_in[9];
    const float* W2  = (const float*)d_in[10];
    const float* b2  = (const float*)d_in[11];
    float* out = (float*)d_out;

    int*   H      = (int*)d_ws;                    // NBUCK*NBLK ints (1.6MB)
    int*   bsum   = H + NBUCK * NBLK;              // pad 2048
    int*   bbase  = bsum + 2048;                   // pad 2048 (NBUCK+1 used)
    unsigned int* sp = (unsigned int*)(bbase + 2048);  // NE packed
    int*   csrc   = (int*)(sp + NE);               // NE
    int*   rowstart = csrc + NE;                   // N
    int*   cntg   = rowstart + NN;                 // N
    float* dinv   = (float*)(cntg + NN);           // N
    ushort_t* Ab  = (ushort_t*)(dinv + NN);        // N*64 bf16 (Yp)
    float* B      = (float*)(Ab + NN * 64);        // N*64 fp32 (agg)
    float* C      = B + NN * 64;                   // N*64 (hres)
    float* Tp     = C + NN * 64;                   // N*2
    float* stats0 = Tp + NN * 2;                   // 128
    float* stats1 = stats0 + 128;                  // 128

    hipMemsetAsync(stats0, 0, 256 * sizeof(float), stream);

    // CSR build: bucket sort by dst>>6, then per-bucket LDS finalize
    kA_hist<<<NBLK, 256, 0, stream>>>(dst, H);
    kB1<<<NBUCK, 256, 0, stream>>>(H, bsum);
    kB2<<<1, 256, 0, stream>>>(bsum, bbase);
    kB3<<<NBUCK, 256, 0, stream>>>(H, bbase);
    kC_scatter<<<NBLK, 256, 0, stream>>>(src, dst, H, sp);
    kD2_fin<<<NBUCK, 256, 0, stream>>>(sp, bbase, csrc, rowstart, cntg, dinv);

    int gemmGrid = (NN + 63) / 64;   // 1563 blocks, 64 rows each
    int aggGrid  = (NN * 64) / 256;  // one wave per node, exact

    // layer 0
    k_gemm64<0><<<gemmGrid, 256, 0, stream>>>(x, W0, nullptr, nullptr, nullptr, dinv, Ab, nullptr);
    k_agg_csr<<<aggGrid, 256, 0, stream>>>(Ab, rowstart, cntg, csrc, dinv, B);
    k_bn_stats<<<256, 256, 0, stream>>>(B, stats0);

    // layer 1 (bn_final folded into gemm)
    k_gemm64<1><<<gemmGrid, 256, 0, stream>>>(B, W1, stats0, g0, be0, dinv, Ab, C);
    k_agg_csr<<<aggGrid, 256, 0, stream>>>(Ab, rowstart, cntg, csrc, dinv, B);
    k_bn_stats<<<256, 256, 0, stream>>>(B, stats1);

    // layer 2 (bn_final folded into gemm_out2)
    k_gemm_out2<<<(NN + 3) / 4, 256, 0, stream>>>(B, stats1, g1, be1, C, W2, dinv, Tp);
    k_out_csr<<<(NN * 8 + 255) / 256, 256, 0, stream>>>(Tp, rowstart, cntg, csrc, dinv, b2, out);
}

// Round 11
// 376.450 us; speedup vs baseline: 4.2949x; 1.1154x over previous
//
#include <hip/hip_runtime.h>

// ResGCN: 3x GCNConv(+BN+ReLU, residual), N=100k, E=1.6M.
// R11: R10 + (1) agg gather ILP: 8 lanes/edge (uint4 of 8 bf16), 16 edges in
// flight per wave (R10 counters: 49us, 30% BW, latency-limited at 8 in flight);
// (2) kB2 parallel scan; (3) kA_hist 1024thr, bn_stats grid 1024 (de-starve).
// b0/b1 skipped (cancelled by BN mean-sub).

#define NN 100000
#define NE 1600000
#define NBUCK 1563        // ceil(NN/64); bucket = dst >> 6
#define NBLK 256          // sort blocks
#define CHUNK 6250        // NE / NBLK exact
#define MAXB 2048         // LDS finalize capacity (avg bucket = 1024)

typedef unsigned short ushort_t;

__device__ __forceinline__ ushort_t f2bf(float f) {  // RTNE
    unsigned u = __float_as_uint(f);
    unsigned r = u + 0x7FFFu + ((u >> 16) & 1u);
    return (ushort_t)(r >> 16);
}
__device__ __forceinline__ float bflo(unsigned u) { return __uint_as_float(u << 16); }
__device__ __forceinline__ float bfhi(unsigned u) { return __uint_as_float(u & 0xFFFF0000u); }

// ---- pass A: per-block bucket histogram (transposed: H[bucket*NBLK + blk]) ----
__launch_bounds__(1024)
__global__ void kA_hist(const int* __restrict__ dst, int* __restrict__ H) {
    __shared__ int h[NBUCK];
    int t = threadIdx.x, blk = blockIdx.x;
    for (int b = t; b < NBUCK; b += 1024) h[b] = 0;
    __syncthreads();
    int e0 = blk * CHUNK;
    for (int e = e0 + t; e < e0 + CHUNK; e += 1024) atomicAdd(&h[dst[e] >> 6], 1);
    __syncthreads();
    for (int b = t; b < NBUCK; b += 1024) H[b * NBLK + blk] = h[b];
}
// ---- pass B1: bucket totals ----
__launch_bounds__(256)
__global__ void kB1(const int* __restrict__ H, int* __restrict__ bsum) {
    __shared__ int sh[256];
    int b = blockIdx.x, t = threadIdx.x;
    sh[t] = H[b * NBLK + t];
    __syncthreads();
    for (int s = 128; s; s >>= 1) {
        if (t < s) sh[t] += sh[t + s];
        __syncthreads();
    }
    if (t == 0) bsum[b] = sh[0];
}
// ---- pass B2: exclusive scan of bucket totals -> bbase[0..NBUCK] (parallel) ----
__global__ void kB2(const int* __restrict__ bsum, int* __restrict__ bbase) {
    __shared__ int part[256];
    int t = threadIdx.x;
    int loc[7];
    int s = 0;
#pragma unroll
    for (int k = 0; k < 7; ++k) {
        int i = t * 7 + k;
        int v = (i < NBUCK) ? bsum[i] : 0;
        loc[k] = s;
        s += v;
    }
    part[t] = s;
    __syncthreads();
    if (t == 0) {
        int acc = 0;
        for (int i = 0; i < 256; ++i) { int v = part[i]; part[i] = acc; acc += v; }
        bbase[NBUCK] = acc;  // == NE
    }
    __syncthreads();
    int base = part[t];
#pragma unroll
    for (int k = 0; k < 7; ++k) {
        int i = t * 7 + k;
        if (i < NBUCK) bbase[i] = base + loc[k];
    }
}
// ---- pass B3: per-(bucket,blk) offsets, in place over H ----
__launch_bounds__(256)
__global__ void kB3(int* __restrict__ H, const int* __restrict__ bbase) {
    __shared__ int sh[256];
    int b = blockIdx.x, t = threadIdx.x;
    sh[t] = H[b * NBLK + t];
    __syncthreads();
    if (t == 0) {
        int acc = bbase[b];
        for (int i = 0; i < 256; ++i) { int v = sh[i]; sh[i] = acc; acc += v; }
    }
    __syncthreads();
    H[b * NBLK + t] = sh[t];
}
// ---- pass C: scatter packed (node6|src24) into bucket order ----
__launch_bounds__(256)
__global__ void kC_scatter(const int* __restrict__ src, const int* __restrict__ dst,
                           const int* __restrict__ O, unsigned int* __restrict__ sp) {
    __shared__ int cur[NBUCK];
    int t = threadIdx.x, blk = blockIdx.x;
    for (int b = t; b < NBUCK; b += 256) cur[b] = O[b * NBLK + blk];
    __syncthreads();
    int e0 = blk * CHUNK;
    for (int e = e0 + t; e < e0 + CHUNK; e += 256) {
        int d = dst[e], s = src[e];
        int p = atomicAdd(&cur[d >> 6], 1);
        sp[p] = ((unsigned int)(d & 63) << 24) | (unsigned int)s;
    }
}
// ---- pass D: per-bucket CSR finalize: csrc dense, rowstart/cnt/dinv ----
__launch_bounds__(256)
__global__ void kD2_fin(const unsigned int* __restrict__ sp, const int* __restrict__ bbase,
                        int* __restrict__ csrc, int* __restrict__ rowstart,
                        int* __restrict__ cntg, float* __restrict__ dinv) {
    __shared__ int cnt[64], ofs[64], cur[64];
    __shared__ int tmp[MAXB];
    int b = blockIdx.x, t = threadIdx.x;
    int beg = bbase[b], end = bbase[b + 1], n = end - beg;
    if (t < 64) cnt[t] = 0;
    __syncthreads();
    for (int i = beg + t; i < end; i += 256) atomicAdd(&cnt[sp[i] >> 24], 1);
    __syncthreads();
    if (t == 0) {
        int acc = 0;
        for (int k = 0; k < 64; ++k) { int v = cnt[k]; ofs[k] = acc; cur[k] = acc; acc += v; }
    }
    __syncthreads();
    int node = b * 64 + t;
    if (t < 64 && node < NN) {
        rowstart[node] = beg + ofs[t];
        cntg[node] = cnt[t];
        dinv[node] = rsqrtf((float)(cnt[t] + 1));
    }
    if (n <= MAXB) {
        for (int i = beg + t; i < end; i += 256) {
            unsigned int v = sp[i];
            int p = atomicAdd(&cur[v >> 24], 1);
            tmp[p] = (int)(v & 0xFFFFFFu);
        }
        __syncthreads();
        for (int i = t; i < n; i += 256) csrc[beg + i] = tmp[i];  // dense, full lines
    } else {  // safety fallback
        for (int i = beg + t; i < end; i += 256) {
            unsigned int v = sp[i];
            int p = atomicAdd(&cur[v >> 24], 1);
            csrc[beg + p] = (int)(v & 0xFFFFFFu);
        }
    }
}

// ---- fused GEMM (N x 64) @ (64 x 64): W column in VGPRs, xs b128 broadcast ----
// 64 rows/block (grid 1563). No barriers: xs[rr] is wave-private.
// MODE 0: Yb = bf16(dinv * (X @ W))
// MODE 1: bn folded (stats/g/be); a = relu(bn(X)); side = a; Yb = bf16(dinv*(a@W))
template <int MODE>
__launch_bounds__(256, 4)
__global__ void k_gemm64(const float* __restrict__ X, const float* __restrict__ W,
                         const float* __restrict__ stats, const float* __restrict__ g,
                         const float* __restrict__ be, const float* __restrict__ dinv,
                         ushort_t* __restrict__ Yb, float* __restrict__ side) {
    __shared__ float xs[4][68];  // per-wave row staging (transpose medium)
    int t = threadIdx.x;
    int c = t & 63, rr = t >> 6;
    float w[64];
#pragma unroll
    for (int k = 0; k < 64; ++k) w[k] = W[k * 64 + c];  // coalesced; L2-resident
    float scale = 1.f, shift = 0.f;
    if (MODE == 1) {  // bn_final folded in
        float mean = stats[c] * (1.0f / NN);
        float var = stats[64 + c] * (1.0f / NN) - mean * mean;
        scale = g[c] * rsqrtf(var + 1e-5f);
        shift = be[c] - mean * scale;
    }
    int base = blockIdx.x * 64;
#pragma unroll 2
    for (int rb = 0; rb < 16; ++rb) {
        int row = base + rb * 4 + rr;
        if (row >= NN) continue;
        float v = X[row * 64 + c];
        if (MODE == 1) {
            v = fmaxf(fmaf(v, scale, shift), 0.f);
            side[row * 64 + c] = v;
        }
        xs[rr][c] = v;  // wave-private: no barrier needed (lgkmcnt ordering)
        const float4* xp = (const float4*)xs[rr];
        float a0 = 0.f, a1 = 0.f, a2 = 0.f, a3 = 0.f;
#pragma unroll
        for (int k4 = 0; k4 < 16; ++k4) {
            float4 xv = xp[k4];  // b128 broadcast (same addr across lanes)
            a0 = fmaf(xv.x, w[k4 * 4 + 0], a0);
            a1 = fmaf(xv.y, w[k4 * 4 + 1], a1);
            a2 = fmaf(xv.z, w[k4 * 4 + 2], a2);
            a3 = fmaf(xv.w, w[k4 * 4 + 3], a3);
        }
        Yb[row * 64 + c] = f2bf(dinv[row] * ((a0 + a1) + (a2 + a3)));
    }
}

// ---- CSR aggregation (bf16 gather, 8 lanes/edge -> 16 edges in flight) ----
// agg[d] = dinv[d]*(Yb[d] + sum Yb[src])
#define ACC8(q)                                                   \
    acc0.x += bflo(q.x); acc0.y += bfhi(q.x);                     \
    acc0.z += bflo(q.y); acc0.w += bfhi(q.y);                     \
    acc1.x += bflo(q.z); acc1.y += bfhi(q.z);                     \
    acc1.z += bflo(q.w); acc1.w += bfhi(q.w);

__launch_bounds__(256)
__global__ void k_agg_csr(const ushort_t* __restrict__ Yb, const int* __restrict__ rowstart,
                          const int* __restrict__ cnt, const int* __restrict__ csrc,
                          const float* __restrict__ dinv, float* __restrict__ agg) {
    int wid = (blockIdx.x * blockDim.x + threadIdx.x) >> 6;  // node
    int lane = threadIdx.x & 63;
    if (wid >= NN) return;
    int grp = lane >> 3;  // 0..7: edge slot
    int l8 = lane & 7;    // 8-channel octet (uint4 = 8 bf16)
    int beg = rowstart[wid], n = cnt[wid];
    float4 acc0 = {0.f, 0.f, 0.f, 0.f}, acc1 = {0.f, 0.f, 0.f, 0.f};
    if (grp == 0) {  // self loop
        uint4 q = ((const uint4*)(Yb + (long)wid * 64))[l8];
        ACC8(q);
    }
    int j = grp;
    for (; j + 8 < n; j += 16) {  // 2 edges in flight per lane-group
        int s0 = csrc[beg + j];
        int s1 = csrc[beg + j + 8];
        uint4 q0 = ((const uint4*)(Yb + (long)s0 * 64))[l8];
        uint4 q1 = ((const uint4*)(Yb + (long)s1 * 64))[l8];
        ACC8(q0);
        ACC8(q1);
    }
    if (j < n) {
        int s = csrc[beg + j];
        uint4 q = ((const uint4*)(Yb + (long)s * 64))[l8];
        ACC8(q);
    }
#pragma unroll
    for (int m = 8; m <= 32; m <<= 1) {
        acc0.x += __shfl_xor(acc0.x, m);
        acc0.y += __shfl_xor(acc0.y, m);
        acc0.z += __shfl_xor(acc0.z, m);
        acc0.w += __shfl_xor(acc0.w, m);
        acc1.x += __shfl_xor(acc1.x, m);
        acc1.y += __shfl_xor(acc1.y, m);
        acc1.z += __shfl_xor(acc1.z, m);
        acc1.w += __shfl_xor(acc1.w, m);
    }
    if (grp == 0) {
        float d = dinv[wid];
        float4 r0 = {acc0.x * d, acc0.y * d, acc0.z * d, acc0.w * d};
        float4 r1 = {acc1.x * d, acc1.y * d, acc1.z * d, acc1.w * d};
        ((float4*)(agg + (long)wid * 64))[l8 * 2] = r0;
        ((float4*)(agg + (long)wid * 64))[l8 * 2 + 1] = r1;
    }
}

// ---- BatchNorm stats (raw sums; finalize folded into consumers) ----
__launch_bounds__(256)
__global__ void k_bn_stats(const float* __restrict__ X, float* __restrict__ stats) {
    __shared__ float sh[512];
    int t = threadIdx.x;
    int c = t & 63, rr = t >> 6;
    float sum = 0.f, sq = 0.f;
    for (int r = blockIdx.x * 4 + rr; r < NN; r += gridDim.x * 4) {
        float v = X[r * 64 + c];
        sum += v;
        sq = fmaf(v, v, sq);
    }
    sh[t] = sum;
    sh[256 + t] = sq;
    __syncthreads();
    if (t < 64) {
        float s = sh[t] + sh[t + 64] + sh[t + 128] + sh[t + 192];
        float q = sh[256 + t] + sh[320 + t] + sh[384 + t] + sh[448 + t];
        atomicAdd(&stats[t], s);
        atomicAdd(&stats[64 + t], q);
    }
}

// ---- final layer GEMM: Tp = dinv * ((relu(bn(X)) + R) @ W2) ----
__launch_bounds__(256)
__global__ void k_gemm_out2(const float* __restrict__ X, const float* __restrict__ stats,
                            const float* __restrict__ g, const float* __restrict__ be,
                            const float* __restrict__ R, const float* __restrict__ W2,
                            const float* __restrict__ dinv, float* __restrict__ Tp) {
    int t = threadIdx.x;
    int lane = t & 63, wv = t >> 6;
    int row = blockIdx.x * 4 + wv;
    if (row >= NN) return;
    float mean = stats[lane] * (1.0f / NN);
    float var = stats[64 + lane] * (1.0f / NN) - mean * mean;
    float scale = g[lane] * rsqrtf(var + 1e-5f);
    float shift = be[lane] - mean * scale;
    float w0 = W2[lane * 2], w1 = W2[lane * 2 + 1];
    float v = X[row * 64 + lane];
    v = fmaxf(fmaf(v, scale, shift), 0.f) + R[row * 64 + lane];
    float p0 = v * w0, p1 = v * w1;
#pragma unroll
    for (int s = 32; s; s >>= 1) {
        p0 += __shfl_xor(p0, s);
        p1 += __shfl_xor(p1, s);
    }
    if (lane == 0) {
        float d = dinv[row];
        Tp[row * 2] = d * p0;
        Tp[row * 2 + 1] = d * p1;
    }
}

// ---- final CSR aggregation, 2 channels, 8 lanes/node ----
__launch_bounds__(256)
__global__ void k_out_csr(const float* __restrict__ Tp, const int* __restrict__ rowstart,
                          const int* __restrict__ cnt, const int* __restrict__ csrc,
                          const float* __restrict__ dinv, const float* __restrict__ b2,
                          float* __restrict__ out) {
    int id = blockIdx.x * blockDim.x + threadIdx.x;
    int node = id >> 3, l = id & 7;
    if (node >= NN) return;
    int beg = rowstart[node], n = cnt[node];
    float a0 = 0.f, a1 = 0.f;
    if (l == 0) { a0 = Tp[node * 2]; a1 = Tp[node * 2 + 1]; }  // self loop
    for (int j = l; j < n; j += 8) {
        int s = csrc[beg + j];
        a0 += Tp[s * 2];
        a1 += Tp[s * 2 + 1];
    }
#pragma unroll
    for (int m = 1; m < 8; m <<= 1) {
        a0 += __shfl_xor(a0, m);
        a1 += __shfl_xor(a1, m);
    }
    if (l == 0) {
        float d = dinv[node];
        out[node * 2] = d * a0 + b2[0];
        out[node * 2 + 1] = d * a1 + b2[1];
    }
}

extern "C" void kernel_launch(void* const* d_in, const int* in_sizes, int n_in,
                              void* d_out, int out_size, void* d_ws, size_t ws_size,
                              hipStream_t stream) {
    const float* x   = (const float*)d_in[0];
    const int*   ei  = (const int*)d_in[1];
    const int*   src = ei;
    const int*   dst = ei + NE;
    const float* W0  = (const float*)d_in[2];
    const float* g0  = (const float*)d_in[4];
    const float* be0 = (const float*)d_in[5];
    const float* W1  = (const float*)d_in[6];
    const float* g1  = (const float*)d_in[8];
    const float* be1 = (const float*)d_in[9];
    const float* W2  = (const float*)d_in[10];
    const float* b2  = (const float*)d_in[11];
    float* out = (float*)d_out;

    int*   H      = (int*)d_ws;                    // NBUCK*NBLK ints (1.6MB)
    int*   bsum   = H + NBUCK * NBLK;              // pad 2048
    int*   bbase  = bsum + 2048;                   // pad 2048 (NBUCK+1 used)
    unsigned int* sp = (unsigned int*)(bbase + 2048);  // NE packed
    int*   csrc   = (int*)(sp + NE);               // NE
    int*   rowstart = csrc + NE;                   // N
    int*   cntg   = rowstart + NN;                 // N
    float* dinv   = (float*)(cntg + NN);           // N
    ushort_t* Ab  = (ushort_t*)(dinv + NN);        // N*64 bf16 (Yp)
    float* B      = (float*)(Ab + NN * 64);        // N*64 fp32 (agg)
    float* C      = B + NN * 64;                   // N*64 (hres)
    float* Tp     = C + NN * 64;                   // N*2
    float* stats0 = Tp + NN * 2;                   // 128
    float* stats1 = stats0 + 128;                  // 128

    hipMemsetAsync(stats0, 0, 256 * sizeof(float), stream);

    // CSR build: bucket sort by dst>>6, then per-bucket LDS finalize
    kA_hist<<<NBLK, 1024, 0, stream>>>(dst, H);
    kB1<<<NBUCK, 256, 0, stream>>>(H, bsum);
    kB2<<<1, 256, 0, stream>>>(bsum, bbase);
    kB3<<<NBUCK, 256, 0, stream>>>(H, bbase);
    kC_scatter<<<NBLK, 256, 0, stream>>>(src, dst, H, sp);
    kD2_fin<<<NBUCK, 256, 0, stream>>>(sp, bbase, csrc, rowstart, cntg, dinv);

    int gemmGrid = (NN + 63) / 64;   // 1563 blocks, 64 rows each
    int aggGrid  = (NN * 64) / 256;  // one wave per node, exact

    // layer 0
    k_gemm64<0><<<gemmGrid, 256, 0, stream>>>(x, W0, nullptr, nullptr, nullptr, dinv, Ab, nullptr);
    k_agg_csr<<<aggGrid, 256, 0, stream>>>(Ab, rowstart, cntg, csrc, dinv, B);
    k_bn_stats<<<1024, 256, 0, stream>>>(B, stats0);

    // layer 1 (bn_final folded into gemm)
    k_gemm64<1><<<gemmGrid, 256, 0, stream>>>(B, W1, stats0, g0, be0, dinv, Ab, C);
    k_agg_csr<<<aggGrid, 256, 0, stream>>>(Ab, rowstart, cntg, csrc, dinv, B);
    k_bn_stats<<<1024, 256, 0, stream>>>(B, stats1);

    // layer 2 (bn_final folded into gemm_out2)
    k_gemm_out2<<<(NN + 3) / 4, 256, 0, stream>>>(B, stats1, g1, be1, C, W2, dinv, Tp);
    k_out_csr<<<(NN * 8 + 255) / 256, 256, 0, stream>>>(Tp, rowstart, cntg, csrc, dinv, b2, out);
}

// Round 12
// 344.642 us; speedup vs baseline: 4.6913x; 1.0923x over previous
//
#include <hip/hip_runtime.h>

// ResGCN: 3x GCNConv(+BN+ReLU, residual), N=100k, E=1.6M.
// R12: replace the VALU gemm64 with MFMA (mfma_f32_16x16x32_bf16).
// R11 counters: gemm64 45us, VALUBusy 22%, occ 27%, VGPR=64 -> compiler never
// kept W in VGPRs; per-row LDS round-trip serialized. MFMA kills the LDS
// transpose: A-frags load straight from global (lane (l&15)=row, (l>>4)*8+e=k),
// W lives in 32 VGPRs as B-frags, C/D layout per verified m89 mapping.
// 100000 = 6250 exact 16-row tiles -> no partial tiles. b0/b1 skipped (BN mean-sub).

#define NN 100000
#define NE 1600000
#define NBUCK 1563        // ceil(NN/64); bucket = dst >> 6
#define NBLK 256          // sort blocks
#define CHUNK 6250        // NE / NBLK exact
#define MAXB 2048         // LDS finalize capacity (avg bucket = 1024)

typedef unsigned short ushort_t;
typedef __attribute__((ext_vector_type(8))) short bf16x8;
typedef __attribute__((ext_vector_type(4))) float f32x4;

__device__ __forceinline__ ushort_t f2bf(float f) {  // RTNE
    unsigned u = __float_as_uint(f);
    unsigned r = u + 0x7FFFu + ((u >> 16) & 1u);
    return (ushort_t)(r >> 16);
}
__device__ __forceinline__ float bflo(unsigned u) { return __uint_as_float(u << 16); }
__device__ __forceinline__ float bfhi(unsigned u) { return __uint_as_float(u & 0xFFFF0000u); }

// ---- pass A: per-block bucket histogram (transposed: H[bucket*NBLK + blk]) ----
__launch_bounds__(1024)
__global__ void kA_hist(const int* __restrict__ dst, int* __restrict__ H) {
    __shared__ int h[NBUCK];
    int t = threadIdx.x, blk = blockIdx.x;
    for (int b = t; b < NBUCK; b += 1024) h[b] = 0;
    __syncthreads();
    int e0 = blk * CHUNK;
    for (int e = e0 + t; e < e0 + CHUNK; e += 1024) atomicAdd(&h[dst[e] >> 6], 1);
    __syncthreads();
    for (int b = t; b < NBUCK; b += 1024) H[b * NBLK + blk] = h[b];
}
// ---- pass B1: bucket totals ----
__launch_bounds__(256)
__global__ void kB1(const int* __restrict__ H, int* __restrict__ bsum) {
    __shared__ int sh[256];
    int b = blockIdx.x, t = threadIdx.x;
    sh[t] = H[b * NBLK + t];
    __syncthreads();
    for (int s = 128; s; s >>= 1) {
        if (t < s) sh[t] += sh[t + s];
        __syncthreads();
    }
    if (t == 0) bsum[b] = sh[0];
}
// ---- pass B2: exclusive scan of bucket totals -> bbase[0..NBUCK] (parallel) ----
__global__ void kB2(const int* __restrict__ bsum, int* __restrict__ bbase) {
    __shared__ int part[256];
    int t = threadIdx.x;
    int loc[7];
    int s = 0;
#pragma unroll
    for (int k = 0; k < 7; ++k) {
        int i = t * 7 + k;
        int v = (i < NBUCK) ? bsum[i] : 0;
        loc[k] = s;
        s += v;
    }
    part[t] = s;
    __syncthreads();
    if (t == 0) {
        int acc = 0;
        for (int i = 0; i < 256; ++i) { int v = part[i]; part[i] = acc; acc += v; }
        bbase[NBUCK] = acc;  // == NE
    }
    __syncthreads();
    int base = part[t];
#pragma unroll
    for (int k = 0; k < 7; ++k) {
        int i = t * 7 + k;
        if (i < NBUCK) bbase[i] = base + loc[k];
    }
}
// ---- pass B3: per-(bucket,blk) offsets, in place over H ----
__launch_bounds__(256)
__global__ void kB3(int* __restrict__ H, const int* __restrict__ bbase) {
    __shared__ int sh[256];
    int b = blockIdx.x, t = threadIdx.x;
    sh[t] = H[b * NBLK + t];
    __syncthreads();
    if (t == 0) {
        int acc = bbase[b];
        for (int i = 0; i < 256; ++i) { int v = sh[i]; sh[i] = acc; acc += v; }
    }
    __syncthreads();
    H[b * NBLK + t] = sh[t];
}
// ---- pass C: scatter packed (node6|src24) into bucket order ----
__launch_bounds__(256)
__global__ void kC_scatter(const int* __restrict__ src, const int* __restrict__ dst,
                           const int* __restrict__ O, unsigned int* __restrict__ sp) {
    __shared__ int cur[NBUCK];
    int t = threadIdx.x, blk = blockIdx.x;
    for (int b = t; b < NBUCK; b += 256) cur[b] = O[b * NBLK + blk];
    __syncthreads();
    int e0 = blk * CHUNK;
    for (int e = e0 + t; e < e0 + CHUNK; e += 256) {
        int d = dst[e], s = src[e];
        int p = atomicAdd(&cur[d >> 6], 1);
        sp[p] = ((unsigned int)(d & 63) << 24) | (unsigned int)s;
    }
}
// ---- pass D: per-bucket CSR finalize: csrc dense, rowstart/cnt/dinv ----
__launch_bounds__(256)
__global__ void kD2_fin(const unsigned int* __restrict__ sp, const int* __restrict__ bbase,
                        int* __restrict__ csrc, int* __restrict__ rowstart,
                        int* __restrict__ cntg, float* __restrict__ dinv) {
    __shared__ int cnt[64], ofs[64], cur[64];
    __shared__ int tmp[MAXB];
    int b = blockIdx.x, t = threadIdx.x;
    int beg = bbase[b], end = bbase[b + 1], n = end - beg;
    if (t < 64) cnt[t] = 0;
    __syncthreads();
    for (int i = beg + t; i < end; i += 256) atomicAdd(&cnt[sp[i] >> 24], 1);
    __syncthreads();
    if (t == 0) {
        int acc = 0;
        for (int k = 0; k < 64; ++k) { int v = cnt[k]; ofs[k] = acc; cur[k] = acc; acc += v; }
    }
    __syncthreads();
    int node = b * 64 + t;
    if (t < 64 && node < NN) {
        rowstart[node] = beg + ofs[t];
        cntg[node] = cnt[t];
        dinv[node] = rsqrtf((float)(cnt[t] + 1));
    }
    if (n <= MAXB) {
        for (int i = beg + t; i < end; i += 256) {
            unsigned int v = sp[i];
            int p = atomicAdd(&cur[v >> 24], 1);
            tmp[p] = (int)(v & 0xFFFFFFu);
        }
        __syncthreads();
        for (int i = t; i < n; i += 256) csrc[beg + i] = tmp[i];  // dense, full lines
    } else {  // safety fallback
        for (int i = beg + t; i < end; i += 256) {
            unsigned int v = sp[i];
            int p = atomicAdd(&cur[v >> 24], 1);
            csrc[beg + p] = (int)(v & 0xFFFFFFu);
        }
    }
}

// ---- MFMA GEMM (N x 64) @ (64 x 64): Yb = bf16(dinv * (act(X) @ W)) ----
// mfma_f32_16x16x32_bf16. A lane map: row=l&15, k=(l>>4)*8+e (two K=32 frags).
// B lane map: col=l&15, k=(l>>4)*8+e. C/D (m89 verified): col=l&15,
// row=(l>>4)*4+reg. Wave does 2 16-row tiles; block 4 waves; grid 782.
// MODE 0: act = identity. MODE 1: act = relu(bn) (stats/g/be), side = act(X).
template <int MODE>
__launch_bounds__(256, 4)
__global__ void k_gemm_mfma(const float* __restrict__ X, const float* __restrict__ W,
                            const float* __restrict__ stats, const float* __restrict__ g,
                            const float* __restrict__ be, const float* __restrict__ dinv,
                            ushort_t* __restrict__ Yb, float* __restrict__ side) {
    int t = threadIdx.x;
    int lane = t & 63, wv = t >> 6;
    int m = lane & 15;   // A row / D col
    int kg = lane >> 4;  // k-group 0..3

    // B-frags: bfr[ct][kf][e] = W[kf*32 + kg*8 + e][ct*16 + m], bf16
    bf16x8 bfr[4][2];
#pragma unroll
    for (int ct = 0; ct < 4; ++ct)
#pragma unroll
        for (int kf = 0; kf < 2; ++kf)
#pragma unroll
            for (int e = 0; e < 8; ++e) {
                int k = kf * 32 + kg * 8 + e;
                bfr[ct][kf][e] = (short)f2bf(W[k * 64 + ct * 16 + m]);
            }

    // bn scale/shift for this lane's 16 k-values (MODE 1)
    float sc[2][8], sh[2][8];
    if (MODE == 1) {
#pragma unroll
        for (int kf = 0; kf < 2; ++kf) {
            int k0 = kf * 32 + kg * 8;
            const f32x4* s4 = (const f32x4*)(stats + k0);
            const f32x4* q4 = (const f32x4*)(stats + 64 + k0);
            const f32x4* g4 = (const f32x4*)(g + k0);
            const f32x4* b4 = (const f32x4*)(be + k0);
#pragma unroll
            for (int h = 0; h < 2; ++h) {
                f32x4 sv = s4[h], qv = q4[h], gv = g4[h], bv = b4[h];
#pragma unroll
                for (int e2 = 0; e2 < 4; ++e2) {
                    float mean = sv[e2] * (1.0f / NN);
                    float var = qv[e2] * (1.0f / NN) - mean * mean;
                    float s = gv[e2] * rsqrtf(var + 1e-5f);
                    sc[kf][h * 4 + e2] = s;
                    sh[kf][h * 4 + e2] = bv[e2] - mean * s;
                }
            }
        }
    }

    int tile0 = blockIdx.x * 8 + wv * 2;
#pragma unroll
    for (int tt = 0; tt < 2; ++tt) {
        int row0 = (tile0 + tt) * 16;
        if (row0 >= NN) break;  // tiles are exact (100000 = 6250*16): full or skip
        long arow = row0 + m;
        bf16x8 afr[2];
#pragma unroll
        for (int kf = 0; kf < 2; ++kf) {
            const f32x4* xp = (const f32x4*)(X + arow * 64 + kf * 32 + kg * 8);
            f32x4 v0 = xp[0], v1 = xp[1];
            if (MODE == 1) {
#pragma unroll
                for (int e = 0; e < 4; ++e) {
                    v0[e] = fmaxf(fmaf(v0[e], sc[kf][e], sh[kf][e]), 0.f);
                    v1[e] = fmaxf(fmaf(v1[e], sc[kf][e + 4], sh[kf][e + 4]), 0.f);
                }
                f32x4* sp2 = (f32x4*)(side + arow * 64 + kf * 32 + kg * 8);
                sp2[0] = v0;
                sp2[1] = v1;
            }
#pragma unroll
            for (int e = 0; e < 4; ++e) {
                afr[kf][e] = (short)f2bf(v0[e]);
                afr[kf][e + 4] = (short)f2bf(v1[e]);
            }
        }
        f32x4 acc0 = {0.f, 0.f, 0.f, 0.f}, acc1 = acc0, acc2 = acc0, acc3 = acc0;
        acc0 = __builtin_amdgcn_mfma_f32_16x16x32_bf16(afr[0], bfr[0][0], acc0, 0, 0, 0);
        acc0 = __builtin_amdgcn_mfma_f32_16x16x32_bf16(afr[1], bfr[0][1], acc0, 0, 0, 0);
        acc1 = __builtin_amdgcn_mfma_f32_16x16x32_bf16(afr[0], bfr[1][0], acc1, 0, 0, 0);
        acc1 = __builtin_amdgcn_mfma_f32_16x16x32_bf16(afr[1], bfr[1][1], acc1, 0, 0, 0);
        acc2 = __builtin_amdgcn_mfma_f32_16x16x32_bf16(afr[0], bfr[2][0], acc2, 0, 0, 0);
        acc2 = __builtin_amdgcn_mfma_f32_16x16x32_bf16(afr[1], bfr[2][1], acc2, 0, 0, 0);
        acc3 = __builtin_amdgcn_mfma_f32_16x16x32_bf16(afr[0], bfr[3][0], acc3, 0, 0, 0);
        acc3 = __builtin_amdgcn_mfma_f32_16x16x32_bf16(afr[1], bfr[3][1], acc3, 0, 0, 0);
#pragma unroll
        for (int r = 0; r < 4; ++r) {
            int grow = row0 + kg * 4 + r;
            float dd = dinv[grow];
            long gb = (long)grow * 64 + m;
            Yb[gb] = f2bf(dd * acc0[r]);
            Yb[gb + 16] = f2bf(dd * acc1[r]);
            Yb[gb + 32] = f2bf(dd * acc2[r]);
            Yb[gb + 48] = f2bf(dd * acc3[r]);
        }
    }
}

// ---- CSR aggregation (bf16 gather, 8 lanes/edge -> 16 edges in flight) ----
// agg[d] = dinv[d]*(Yb[d] + sum Yb[src])
#define ACC8(q)                                                   \
    acc0.x += bflo(q.x); acc0.y += bfhi(q.x);                     \
    acc0.z += bflo(q.y); acc0.w += bfhi(q.y);                     \
    acc1.x += bflo(q.z); acc1.y += bfhi(q.z);                     \
    acc1.z += bflo(q.w); acc1.w += bfhi(q.w);

__launch_bounds__(256)
__global__ void k_agg_csr(const ushort_t* __restrict__ Yb, const int* __restrict__ rowstart,
                          const int* __restrict__ cnt, const int* __restrict__ csrc,
                          const float* __restrict__ dinv, float* __restrict__ agg) {
    int wid = (blockIdx.x * blockDim.x + threadIdx.x) >> 6;  // node
    int lane = threadIdx.x & 63;
    if (wid >= NN) return;
    int grp = lane >> 3;  // 0..7: edge slot
    int l8 = lane & 7;    // 8-channel octet (uint4 = 8 bf16)
    int beg = rowstart[wid], n = cnt[wid];
    float4 acc0 = {0.f, 0.f, 0.f, 0.f}, acc1 = {0.f, 0.f, 0.f, 0.f};
    if (grp == 0) {  // self loop
        uint4 q = ((const uint4*)(Yb + (long)wid * 64))[l8];
        ACC8(q);
    }
    int j = grp;
    for (; j + 8 < n; j += 16) {  // 2 edges in flight per lane-group
        int s0 = csrc[beg + j];
        int s1 = csrc[beg + j + 8];
        uint4 q0 = ((const uint4*)(Yb + (long)s0 * 64))[l8];
        uint4 q1 = ((const uint4*)(Yb + (long)s1 * 64))[l8];
        ACC8(q0);
        ACC8(q1);
    }
    if (j < n) {
        int s = csrc[beg + j];
        uint4 q = ((const uint4*)(Yb + (long)s * 64))[l8];
        ACC8(q);
    }
#pragma unroll
    for (int m = 8; m <= 32; m <<= 1) {
        acc0.x += __shfl_xor(acc0.x, m);
        acc0.y += __shfl_xor(acc0.y, m);
        acc0.z += __shfl_xor(acc0.z, m);
        acc0.w += __shfl_xor(acc0.w, m);
        acc1.x += __shfl_xor(acc1.x, m);
        acc1.y += __shfl_xor(acc1.y, m);
        acc1.z += __shfl_xor(acc1.z, m);
        acc1.w += __shfl_xor(acc1.w, m);
    }
    if (grp == 0) {
        float d = dinv[wid];
        float4 r0 = {acc0.x * d, acc0.y * d, acc0.z * d, acc0.w * d};
        float4 r1 = {acc1.x * d, acc1.y * d, acc1.z * d, acc1.w * d};
        ((float4*)(agg + (long)wid * 64))[l8 * 2] = r0;
        ((float4*)(agg + (long)wid * 64))[l8 * 2 + 1] = r1;
    }
}

// ---- BatchNorm stats (raw sums; finalize folded into consumers) ----
__launch_bounds__(256)
__global__ void k_bn_stats(const float* __restrict__ X, float* __restrict__ stats) {
    __shared__ float sh[512];
    int t = threadIdx.x;
    int c = t & 63, rr = t >> 6;
    float sum = 0.f, sq = 0.f;
    for (int r = blockIdx.x * 4 + rr; r < NN; r += gridDim.x * 4) {
        float v = X[r * 64 + c];
        sum += v;
        sq = fmaf(v, v, sq);
    }
    sh[t] = sum;
    sh[256 + t] = sq;
    __syncthreads();
    if (t < 64) {
        float s = sh[t] + sh[t + 64] + sh[t + 128] + sh[t + 192];
        float q = sh[256 + t] + sh[320 + t] + sh[384 + t] + sh[448 + t];
        atomicAdd(&stats[t], s);
        atomicAdd(&stats[64 + t], q);
    }
}

// ---- final layer GEMM: Tp = dinv * ((relu(bn(X)) + R) @ W2) ----
__launch_bounds__(256)
__global__ void k_gemm_out2(const float* __restrict__ X, const float* __restrict__ stats,
                            const float* __restrict__ g, const float* __restrict__ be,
                            const float* __restrict__ R, const float* __restrict__ W2,
                            const float* __restrict__ dinv, float* __restrict__ Tp) {
    int t = threadIdx.x;
    int lane = t & 63, wv = t >> 6;
    int row = blockIdx.x * 4 + wv;
    if (row >= NN) return;
    float mean = stats[lane] * (1.0f / NN);
    float var = stats[64 + lane] * (1.0f / NN) - mean * mean;
    float scale = g[lane] * rsqrtf(var + 1e-5f);
    float shift = be[lane] - mean * scale;
    float w0 = W2[lane * 2], w1 = W2[lane * 2 + 1];
    float v = X[row * 64 + lane];
    v = fmaxf(fmaf(v, scale, shift), 0.f) + R[row * 64 + lane];
    float p0 = v * w0, p1 = v * w1;
#pragma unroll
    for (int s = 32; s; s >>= 1) {
        p0 += __shfl_xor(p0, s);
        p1 += __shfl_xor(p1, s);
    }
    if (lane == 0) {
        float d = dinv[row];
        Tp[row * 2] = d * p0;
        Tp[row * 2 + 1] = d * p1;
    }
}

// ---- final CSR aggregation, 2 channels, 8 lanes/node ----
__launch_bounds__(256)
__global__ void k_out_csr(const float* __restrict__ Tp, const int* __restrict__ rowstart,
                          const int* __restrict__ cnt, const int* __restrict__ csrc,
                          const float* __restrict__ dinv, const float* __restrict__ b2,
                          float* __restrict__ out) {
    int id = blockIdx.x * blockDim.x + threadIdx.x;
    int node = id >> 3, l = id & 7;
    if (node >= NN) return;
    int beg = rowstart[node], n = cnt[node];
    float a0 = 0.f, a1 = 0.f;
    if (l == 0) { a0 = Tp[node * 2]; a1 = Tp[node * 2 + 1]; }  // self loop
    for (int j = l; j < n; j += 8) {
        int s = csrc[beg + j];
        a0 += Tp[s * 2];
        a1 += Tp[s * 2 + 1];
    }
#pragma unroll
    for (int m = 1; m < 8; m <<= 1) {
        a0 += __shfl_xor(a0, m);
        a1 += __shfl_xor(a1, m);
    }
    if (l == 0) {
        float d = dinv[node];
        out[node * 2] = d * a0 + b2[0];
        out[node * 2 + 1] = d * a1 + b2[1];
    }
}

extern "C" void kernel_launch(void* const* d_in, const int* in_sizes, int n_in,
                              void* d_out, int out_size, void* d_ws, size_t ws_size,
                              hipStream_t stream) {
    const float* x   = (const float*)d_in[0];
    const int*   ei  = (const int*)d_in[1];
    const int*   src = ei;
    const int*   dst = ei + NE;
    const float* W0  = (const float*)d_in[2];
    const float* g0  = (const float*)d_in[4];
    const float* be0 = (const float*)d_in[5];
    const float* W1  = (const float*)d_in[6];
    const float* g1  = (const float*)d_in[8];
    const float* be1 = (const float*)d_in[9];
    const float* W2  = (const float*)d_in[10];
    const float* b2  = (const float*)d_in[11];
    float* out = (float*)d_out;

    int*   H      = (int*)d_ws;                    // NBUCK*NBLK ints (1.6MB)
    int*   bsum   = H + NBUCK * NBLK;              // pad 2048
    int*   bbase  = bsum + 2048;                   // pad 2048 (NBUCK+1 used)
    unsigned int* sp = (unsigned int*)(bbase + 2048);  // NE packed
    int*   csrc   = (int*)(sp + NE);               // NE
    int*   rowstart = csrc + NE;                   // N
    int*   cntg   = rowstart + NN;                 // N
    float* dinv   = (float*)(cntg + NN);           // N
    ushort_t* Ab  = (ushort_t*)(dinv + NN);        // N*64 bf16 (Yp)
    float* B      = (float*)(Ab + NN * 64);        // N*64 fp32 (agg)
    float* C      = B + NN * 64;                   // N*64 (hres)
    float* Tp     = C + NN * 64;                   // N*2
    float* stats0 = Tp + NN * 2;                   // 128
    float* stats1 = stats0 + 128;                  // 128

    hipMemsetAsync(stats0, 0, 256 * sizeof(float), stream);

    // CSR build: bucket sort by dst>>6, then per-bucket LDS finalize
    kA_hist<<<NBLK, 1024, 0, stream>>>(dst, H);
    kB1<<<NBUCK, 256, 0, stream>>>(H, bsum);
    kB2<<<1, 256, 0, stream>>>(bsum, bbase);
    kB3<<<NBUCK, 256, 0, stream>>>(H, bbase);
    kC_scatter<<<NBLK, 256, 0, stream>>>(src, dst, H, sp);
    kD2_fin<<<NBUCK, 256, 0, stream>>>(sp, bbase, csrc, rowstart, cntg, dinv);

    int mfmaGrid = 782;              // 6250 16-row tiles / 8 tiles per block
    int aggGrid  = (NN * 64) / 256;  // one wave per node, exact

    // layer 0
    k_gemm_mfma<0><<<mfmaGrid, 256, 0, stream>>>(x, W0, nullptr, nullptr, nullptr, dinv, Ab, nullptr);
    k_agg_csr<<<aggGrid, 256, 0, stream>>>(Ab, rowstart, cntg, csrc, dinv, B);
    k_bn_stats<<<1024, 256, 0, stream>>>(B, stats0);

    // layer 1 (bn folded into the A-frag load)
    k_gemm_mfma<1><<<mfmaGrid, 256, 0, stream>>>(B, W1, stats0, g0, be0, dinv, Ab, C);
    k_agg_csr<<<aggGrid, 256, 0, stream>>>(Ab, rowstart, cntg, csrc, dinv, B);
    k_bn_stats<<<1024, 256, 0, stream>>>(B, stats1);

    // layer 2 (bn folded into gemm_out2)
    k_gemm_out2<<<(NN + 3) / 4, 256, 0, stream>>>(B, stats1, g1, be1, C, W2, dinv, Tp);
    k_out_csr<<<(NN * 8 + 255) / 256, 256, 0, stream>>>(Tp, rowstart, cntg, csrc, dinv, b2, out);
}